// Round 3
// baseline (1625.264 us; speedup 1.0000x reference)
//
#include <hip/hip_runtime.h>
#include <stdint.h>

#define N_S 30000
#define N_G 3000
#define DD  128
#define KK  16
#define NE  (N_G * KK)

// Only device-side-accessed global state (never passed as a kernel arg from host).
__device__ int g_flag;   // 1 = tensors are bf16, 0 = f32

__device__ __forceinline__ float bf2f(unsigned short u) {
    union { unsigned int i; float f; } v; v.i = ((unsigned int)u) << 16; return v.f;
}
__device__ __forceinline__ unsigned short f2bf(float f) {
    union { float f; unsigned int i; } v; v.f = f;
    unsigned int x = v.i;
    return (unsigned short)((x + 0x7fffu + ((x >> 16) & 1u)) >> 16);
}
__device__ __forceinline__ float ldIn(const void* p, int i, int bf) {
    return bf ? bf2f(((const unsigned short*)p)[i]) : ((const float*)p)[i];
}
__device__ __forceinline__ void stOut(void* p, int i, float v, int bf) {
    if (bf) ((unsigned short*)p)[i] = f2bf(v);
    else    ((float*)p)[i] = v;
}

// dtype detection: bf16 coords in [0.25,60] -> high byte of each u16 in [0x3E,0x42]
// (sign=0, exponent 0x7D..0x84 >> 1). f32 data puts ~uniform mantissa bits there.
__global__ void detect_kernel(const void* pos_g) {
    const unsigned int* w = (const unsigned int*)pos_g;
    __shared__ int sv[256];
    const int t = threadIdx.x;
    int votes = 0;
    for (int i = t; i < 4500; i += 256) {
        unsigned int b = (w[i] >> 8) & 0xFFu;
        if (b >= 0x3Eu && b <= 0x42u) votes++;
    }
    sv[t] = votes; __syncthreads();
    for (int o = 128; o > 0; o >>= 1) {
        if (t < o) sv[t] += sv[t + o];
        __syncthreads();
    }
    if (t == 0) g_flag = (sv[0] > 2250) ? 1 : 0;
}

// ---------------------------------------------------------------------------
// kNN: exact f64 distances (bit-exact for bf16/f32-origin coords), tie-break
// by lower surface index. One block (256 thr) per graph node; per-thread
// sorted top-16 list, then 256-way merge by wave 0 (sentinel-guarded).
// ---------------------------------------------------------------------------
__global__ __launch_bounds__(256) void knn_kernel(const void* pos_s, const void* pos_g,
                                                  int* __restrict__ idx_out,
                                                  float* __restrict__ w_out) {
    __shared__ float  ps[3072];
    __shared__ double skeys[256 * KK];
    __shared__ int    ssidx[256 * KK];

    const int g = blockIdx.x;
    const int t = threadIdx.x;
    const int bf = g_flag;

    const double gx = (double)ldIn(pos_g, 3 * g + 0, bf);
    const double gy = (double)ldIn(pos_g, 3 * g + 1, bf);
    const double gz = (double)ldIn(pos_g, 3 * g + 2, bf);

    double bk[KK]; int bi[KK];
#pragma unroll
    for (int j = 0; j < KK; ++j) { bk[j] = 1e300; bi[j] = 0x7fffffff; }

    for (int c0 = 0; c0 < N_S; c0 += 1024) {
        const int npts = (N_S - c0 < 1024) ? (N_S - c0) : 1024;
        const int nval = npts * 3;
        __syncthreads();
        for (int u = t; u < nval; u += 256) ps[u] = ldIn(pos_s, c0 * 3 + u, bf);
        __syncthreads();
        for (int l = t; l < npts; l += 256) {
            const int s = c0 + l;
            const double dx = gx - (double)ps[3 * l + 0];
            const double dy = gy - (double)ps[3 * l + 1];
            const double dz = gz - (double)ps[3 * l + 2];
            const double d2 = dx * dx + dy * dy + dz * dz;
            if (d2 > bk[KK - 1]) continue;
            if (d2 == bk[KK - 1] && s > bi[KK - 1]) continue;
            double ck = d2; int ci = s;
#pragma unroll
            for (int j = 0; j < KK; ++j) {
                const bool less = (ck < bk[j]) || (ck == bk[j] && ci < bi[j]);
                const double nk = less ? ck : bk[j]; const int ni = less ? ci : bi[j];
                const double ok = less ? bk[j] : ck; const int oi = less ? bi[j] : ci;
                bk[j] = nk; bi[j] = ni; ck = ok; ci = oi;
            }
        }
    }
    __syncthreads();
#pragma unroll
    for (int j = 0; j < KK; ++j) { skeys[t * KK + j] = bk[j]; ssidx[t * KK + j] = bi[j]; }
    __syncthreads();

    if (t < 64) {
        int h0 = 0, h1 = 0, h2 = 0, h3 = 0;
        const int b0 = (4 * t + 0) * KK, b1 = (4 * t + 1) * KK;
        const int b2 = (4 * t + 2) * KK, b3 = (4 * t + 3) * KK;
        for (int p = 0; p < KK; ++p) {
            double k0 = (h0 < KK) ? skeys[b0 + h0] : 1e300;
            double k1 = (h1 < KK) ? skeys[b1 + h1] : 1e300;
            double k2 = (h2 < KK) ? skeys[b2 + h2] : 1e300;
            double k3 = (h3 < KK) ? skeys[b3 + h3] : 1e300;
            int s0 = (h0 < KK) ? ssidx[b0 + h0] : 0x7fffffff;
            int s1 = (h1 < KK) ? ssidx[b1 + h1] : 0x7fffffff;
            int s2 = (h2 < KK) ? ssidx[b2 + h2] : 0x7fffffff;
            int s3 = (h3 < KK) ? ssidx[b3 + h3] : 0x7fffffff;
            double ka; int sa; int la;
            if (k1 < k0 || (k1 == k0 && s1 < s0)) { ka = k1; sa = s1; la = 1; }
            else                                  { ka = k0; sa = s0; la = 0; }
            if (k2 < ka || (k2 == ka && s2 < sa)) { ka = k2; sa = s2; la = 2; }
            if (k3 < ka || (k3 == ka && s3 < sa)) { ka = k3; sa = s3; la = 3; }
            double bkey = ka; int bs = sa; int bwho = (t << 2) | la;
            for (int d = 1; d < 64; d <<= 1) {
                const double ok = __shfl_xor(bkey, d);
                const int    os = __shfl_xor(bs, d);
                const int    ow = __shfl_xor(bwho, d);
                if (ok < bkey || (ok == bkey && os < bs)) { bkey = ok; bs = os; bwho = ow; }
            }
            if (t == 0) {
                idx_out[g * KK + p] = bs;
                w_out[g * KK + p] = expf((float)(-bkey) * (1.0f / 12.5f));
            }
            if ((bwho >> 2) == t) {
                const int wl = bwho & 3;
                if (wl == 0) ++h0; else if (wl == 1) ++h1; else if (wl == 2) ++h2; else ++h3;
            }
        }
    }
}

// out[M x 128] = A[M x 128] @ W[128 x 128], f32 accumulate/out. 16 rows/block.
__global__ __launch_bounds__(128) void gemm_kernel(const void* A, const void* W,
                                                   float* __restrict__ out, int M) {
    __shared__ float a[16][DD];
    const int j = threadIdx.x;
    const int base = blockIdx.x * 16;
    const int bf = g_flag;
    for (int r = 0; r < 16; ++r) {
        const int row = base + r;
        a[r][j] = (row < M) ? ldIn(A, row * DD + j, bf) : 0.f;
    }
    __syncthreads();
    float acc[16];
#pragma unroll
    for (int r = 0; r < 16; ++r) acc[r] = 0.f;
    for (int i = 0; i < DD; ++i) {
        const float wv = ldIn(W, i * DD + j, bf);
#pragma unroll
        for (int r = 0; r < 16; ++r) acc[r] += a[r][i] * wv;
    }
    for (int r = 0; r < 16; ++r) {
        const int row = base + r;
        if (row < M) out[row * DD + j] = acc[r];
    }
}

// Wf[i][j] = sum_m W1[i][m] * Wp[128+m][j]  (fold message GEMM into post-GEMM)
__global__ __launch_bounds__(128) void wfuse_kernel(const void* W1, const void* Wp,
                                                    float* __restrict__ Wf) {
    __shared__ float row[DD];
    const int i = blockIdx.x, j = threadIdx.x, bf = g_flag;
    row[j] = ldIn(W1, i * DD + j, bf);
    __syncthreads();
    float acc = 0.f;
    for (int m = 0; m < DD; ++m) acc += row[m] * ldIn(Wp, (DD + m) * DD + j, bf);
    Wf[i * DD + j] = acc;
}

// ---- reverse-CSR build (graph->surface edges grouped by surface node) ----
__global__ void zero_cnt_kernel(int* __restrict__ cnt) {
    const int i = blockIdx.x * 256 + threadIdx.x;
    if (i < N_S) cnt[i] = 0;
}
__global__ void count_kernel(const int* __restrict__ idx, int* __restrict__ cnt) {
    const int e = blockIdx.x * 256 + threadIdx.x;
    if (e < NE) atomicAdd(&cnt[idx[e]], 1);
}
__global__ void scan_kernel(const int* __restrict__ cnt, int* __restrict__ off,
                            int* __restrict__ cur) {
    __shared__ int buf[256];
    __shared__ int carry;
    const int t = threadIdx.x;
    if (t == 0) carry = 0;
    __syncthreads();
    for (int c0 = 0; c0 < N_S; c0 += 256) {
        const int i = c0 + t;
        const int v = (i < N_S) ? cnt[i] : 0;
        buf[t] = v;
        __syncthreads();
        for (int o = 1; o < 256; o <<= 1) {
            const int x = (t >= o) ? buf[t - o] : 0;
            __syncthreads();
            buf[t] += x;
            __syncthreads();
        }
        const int base_c = carry;
        const int excl = buf[t] - v;
        if (i < N_S) { off[i] = base_c + excl; cur[i] = base_c + excl; }
        __syncthreads();
        if (t == 0) carry = base_c + buf[255];
        __syncthreads();
    }
}
__global__ void fill_kernel(const int* __restrict__ idx, const float* __restrict__ w,
                            int* __restrict__ cur, int* __restrict__ rg,
                            float* __restrict__ rw) {
    const int e = blockIdx.x * 256 + threadIdx.x;
    if (e < NE) {
        const int s = idx[e];
        const int p = atomicAdd(&cur[s], 1);
        rg[p] = e >> 4;        // source graph node
        rw[p] = w[e];
    }
}

// out_s = relu(hs @ Wp_top + (sum_incoming w*hg[g]) @ Wfs), 16 rows/block.
__global__ __launch_bounds__(128) void final_s_kernel(
    const float* __restrict__ hs, const float* __restrict__ hg,
    const int* __restrict__ off, const int* __restrict__ cnt,
    const int* __restrict__ rg, const float* __restrict__ rw,
    const void* Wp, const float* __restrict__ wfs, void* out) {
    __shared__ float a1[16][DD];
    __shared__ float a2[16][DD];
    const int j = threadIdx.x;
    const int base = blockIdx.x * 16;
    const int bf = g_flag;
    for (int r = 0; r < 16; ++r) {
        const int row = base + r;
        a1[r][j] = hs[row * DD + j];
        float acc = 0.f;
        const int o = off[row], c = cnt[row];
        for (int e = 0; e < c; ++e) acc += rw[o + e] * hg[rg[o + e] * DD + j];
        a2[r][j] = acc;
    }
    __syncthreads();
    float acc[16];
#pragma unroll
    for (int r = 0; r < 16; ++r) acc[r] = 0.f;
    for (int i = 0; i < DD; ++i) {
        const float w1 = ldIn(Wp, i * DD + j, bf);
#pragma unroll
        for (int r = 0; r < 16; ++r) acc[r] += a1[r][i] * w1;
    }
    for (int i = 0; i < DD; ++i) {
        const float w2 = wfs[i * DD + j];
#pragma unroll
        for (int r = 0; r < 16; ++r) acc[r] += a2[r][i] * w2;
    }
    for (int r = 0; r < 16; ++r) {
        const int row = base + r;
        const float v = acc[r] > 0.f ? acc[r] : 0.f;
        stOut(out, row * DD + j, v, bf);
    }
}

// out_g = relu(hg @ Wp_top + (sum_k w*hs[idx]) @ Wfg) at element offset N_S*DD.
__global__ __launch_bounds__(128) void final_g_kernel(
    const float* __restrict__ hs, const float* __restrict__ hg,
    const int* __restrict__ idx, const float* __restrict__ w,
    const void* Wp, const float* __restrict__ wfg, void* out) {
    __shared__ float a1[16][DD];
    __shared__ float a2[16][DD];
    const int j = threadIdx.x;
    const int base = blockIdx.x * 16;
    const int bf = g_flag;
    for (int r = 0; r < 16; ++r) {
        const int row = base + r;
        if (row < N_G) {
            a1[r][j] = hg[row * DD + j];
            float acc = 0.f;
#pragma unroll
            for (int k = 0; k < KK; ++k)
                acc += w[row * KK + k] * hs[idx[row * KK + k] * DD + j];
            a2[r][j] = acc;
        } else { a1[r][j] = 0.f; a2[r][j] = 0.f; }
    }
    __syncthreads();
    float acc[16];
#pragma unroll
    for (int r = 0; r < 16; ++r) acc[r] = 0.f;
    for (int i = 0; i < DD; ++i) {
        const float w1 = ldIn(Wp, i * DD + j, bf);
#pragma unroll
        for (int r = 0; r < 16; ++r) acc[r] += a1[r][i] * w1;
    }
    for (int i = 0; i < DD; ++i) {
        const float w2 = wfg[i * DD + j];
#pragma unroll
        for (int r = 0; r < 16; ++r) acc[r] += a2[r][i] * w2;
    }
    for (int r = 0; r < 16; ++r) {
        const int row = base + r;
        if (row < N_G) {
            const float v = acc[r] > 0.f ? acc[r] : 0.f;
            stOut(out, N_S * DD + row * DD + j, v, bf);
        }
    }
}

extern "C" void kernel_launch(void* const* d_in, const int* in_sizes, int n_in,
                              void* d_out, int out_size, void* d_ws, size_t ws_size,
                              hipStream_t stream)
{
    const void* xs       = d_in[0];
    const void* xg       = d_in[1];
    const void* pos_s    = d_in[2];
    const void* pos_g    = d_in[3];
    const void* W_s_pre  = d_in[4];
    const void* W_g_pre  = d_in[5];
    const void* W_gs     = d_in[6];
    const void* W_sg     = d_in[7];
    const void* W_s_post = d_in[8];
    const void* W_g_post = d_in[9];
    (void)in_sizes; (void)n_in; (void)out_size; (void)ws_size;

    // scratch carve-out from d_ws (~18.1 MB; round 1 proved ws >= ~34 MB works)
    char* ws = (char*)d_ws;
    size_t off_b = 0;
    auto alloc = [&](size_t bytes) -> void* {
        void* p = ws + off_b;
        off_b = (off_b + bytes + 255) & ~((size_t)255);
        return p;
    };
    float* hs   = (float*)alloc((size_t)N_S * DD * 4);
    float* hg   = (float*)alloc((size_t)N_G * DD * 4);
    float* wfs  = (float*)alloc((size_t)DD * DD * 4);
    float* wfg  = (float*)alloc((size_t)DD * DD * 4);
    int*   idx  = (int*)  alloc((size_t)NE * 4);
    float* w    = (float*)alloc((size_t)NE * 4);
    int*   cnt  = (int*)  alloc((size_t)N_S * 4);
    int*   offs = (int*)  alloc((size_t)N_S * 4);
    int*   cur  = (int*)  alloc((size_t)N_S * 4);
    int*   rg   = (int*)  alloc((size_t)NE * 4);
    float* rw   = (float*)alloc((size_t)NE * 4);

    detect_kernel<<<1, 256, 0, stream>>>(pos_g);
    knn_kernel<<<N_G, 256, 0, stream>>>(pos_s, pos_g, idx, w);
    gemm_kernel<<<(N_S + 15) / 16, 128, 0, stream>>>(xs, W_s_pre, hs, N_S);
    gemm_kernel<<<(N_G + 15) / 16, 128, 0, stream>>>(xg, W_g_pre, hg, N_G);
    zero_cnt_kernel<<<(N_S + 255) / 256, 256, 0, stream>>>(cnt);
    count_kernel<<<(NE + 255) / 256, 256, 0, stream>>>(idx, cnt);
    scan_kernel<<<1, 256, 0, stream>>>(cnt, offs, cur);
    fill_kernel<<<(NE + 255) / 256, 256, 0, stream>>>(idx, w, cur, rg, rw);
    wfuse_kernel<<<DD, DD, 0, stream>>>(W_gs, W_s_post, wfs);
    wfuse_kernel<<<DD, DD, 0, stream>>>(W_sg, W_g_post, wfg);
    final_s_kernel<<<N_S / 16, 128, 0, stream>>>(hs, hg, offs, cnt, rg, rw,
                                                 W_s_post, wfs, d_out);
    final_g_kernel<<<(N_G + 15) / 16, 128, 0, stream>>>(hs, hg, idx, w,
                                                        W_g_post, wfg, d_out);
}

// Round 4
// 514.437 us; speedup vs baseline: 3.1593x; 3.1593x over previous
//
#include <hip/hip_runtime.h>
#include <stdint.h>

#define N_S 30000
#define N_G 3000
#define DD  128
#define KK  16
#define NE  (N_G * KK)
#define NC  16            // cells per axis
#define CELLS (NC * NC * NC)
#define CH  3.75f         // cell size (60/16), exactly representable

// Only device-side-accessed global state (never passed as a kernel arg from host).
__device__ int g_flag;   // 1 = tensors are bf16, 0 = f32

__device__ __forceinline__ float bf2f(unsigned short u) {
    union { unsigned int i; float f; } v; v.i = ((unsigned int)u) << 16; return v.f;
}
__device__ __forceinline__ unsigned short f2bf(float f) {
    union { float f; unsigned int i; } v; v.f = f;
    unsigned int x = v.i;
    return (unsigned short)((x + 0x7fffu + ((x >> 16) & 1u)) >> 16);
}
__device__ __forceinline__ float ldIn(const void* p, int i, int bf) {
    return bf ? bf2f(((const unsigned short*)p)[i]) : ((const float*)p)[i];
}
__device__ __forceinline__ void stOut(void* p, int i, float v, int bf) {
    if (bf) ((unsigned short*)p)[i] = f2bf(v);
    else    ((float*)p)[i] = v;
}
__device__ __forceinline__ int cellOf(float x) {
    int c = (int)(x * (1.0f / CH));
    if (c < 0) c = 0; if (c > NC - 1) c = NC - 1;
    return c;
}

// dtype detection: bf16 coords in [0.25,60] -> high byte of each u16 in [0x3E,0x42].
__global__ void detect_kernel(const void* pos_g) {
    const unsigned int* w = (const unsigned int*)pos_g;
    __shared__ int sv[256];
    const int t = threadIdx.x;
    int votes = 0;
    for (int i = t; i < 4500; i += 256) {
        unsigned int b = (w[i] >> 8) & 0xFFu;
        if (b >= 0x3Eu && b <= 0x42u) votes++;
    }
    sv[t] = votes; __syncthreads();
    for (int o = 128; o > 0; o >>= 1) {
        if (t < o) sv[t] += sv[t + o];
        __syncthreads();
    }
    if (t == 0) g_flag = (sv[0] > 2250) ? 1 : 0;
}

// ---- generic zero / count / scan / fill helpers ----
__global__ void zero_kernel(int* __restrict__ p, int n) {
    const int i = blockIdx.x * 256 + threadIdx.x;
    if (i < n) p[i] = 0;
}
__global__ void cell_count_kernel(const void* pos_s, int* __restrict__ ccnt) {
    const int p = blockIdx.x * 256 + threadIdx.x;
    if (p < N_S) {
        const int bf = g_flag;
        const int cx = cellOf(ldIn(pos_s, 3 * p + 0, bf));
        const int cy = cellOf(ldIn(pos_s, 3 * p + 1, bf));
        const int cz = cellOf(ldIn(pos_s, 3 * p + 2, bf));
        atomicAdd(&ccnt[(cx * NC + cy) * NC + cz], 1);
    }
}
// exclusive scan of cnt[0..n) -> off, cur  (single block, 256 threads)
__global__ void scan_kernel(const int* __restrict__ cnt, int* __restrict__ off,
                            int* __restrict__ cur, int n) {
    __shared__ int buf[256];
    __shared__ int carry;
    const int t = threadIdx.x;
    if (t == 0) carry = 0;
    __syncthreads();
    for (int c0 = 0; c0 < n; c0 += 256) {
        const int i = c0 + t;
        const int v = (i < n) ? cnt[i] : 0;
        buf[t] = v;
        __syncthreads();
        for (int o = 1; o < 256; o <<= 1) {
            const int x = (t >= o) ? buf[t - o] : 0;
            __syncthreads();
            buf[t] += x;
            __syncthreads();
        }
        const int base_c = carry;
        const int excl = buf[t] - v;
        if (i < n) { off[i] = base_c + excl; cur[i] = base_c + excl; }
        __syncthreads();
        if (t == 0) carry = base_c + buf[255];
        __syncthreads();
    }
}
__global__ void cell_fill_kernel(const void* pos_s, int* __restrict__ ccur,
                                 float4* __restrict__ scell) {
    const int p = blockIdx.x * 256 + threadIdx.x;
    if (p < N_S) {
        const int bf = g_flag;
        const float x = ldIn(pos_s, 3 * p + 0, bf);
        const float y = ldIn(pos_s, 3 * p + 1, bf);
        const float z = ldIn(pos_s, 3 * p + 2, bf);
        const int cid = (cellOf(x) * NC + cellOf(y)) * NC + cellOf(z);
        const int slot = atomicAdd(&ccur[cid], 1);
        scell[slot] = make_float4(x, y, z, __int_as_float(p));
    }
}

// ---------------------------------------------------------------------------
// Grid-accelerated exact kNN. One 64-thread block (one wave) per graph node.
// f64 distances (exact for bf16/f32-origin coords), lower-index tie-break.
// Shell expansion with conservative stop rule => identical result to brute force.
// ---------------------------------------------------------------------------
__global__ __launch_bounds__(64) void knn_grid_kernel(
    const void* pos_g,
    const int* __restrict__ coff, const int* __restrict__ ccnt,
    const float4* __restrict__ scell,
    int* __restrict__ idx_out, float* __restrict__ w_out)
{
    __shared__ int    c_start[64];
    __shared__ int    c_pref[64];
    __shared__ double skeys[64 * KK];
    __shared__ int    ssidx[64 * KK];

    const int g = blockIdx.x;
    const int t = threadIdx.x;
    const int bf = g_flag;

    const float gxf = ldIn(pos_g, 3 * g + 0, bf);
    const float gyf = ldIn(pos_g, 3 * g + 1, bf);
    const float gzf = ldIn(pos_g, 3 * g + 2, bf);
    const double gx = (double)gxf, gy = (double)gyf, gz = (double)gzf;
    const int cx = cellOf(gxf), cy = cellOf(gyf), cz = cellOf(gzf);

    double bk[KK]; int bi[KK];
#pragma unroll
    for (int j = 0; j < KK; ++j) { bk[j] = 1e300; bi[j] = 0x7fffffff; }

    bool done = false;
    for (int R = 1; R <= NC && !done; ++R) {
        const int S = 2 * R + 1;
        const int Scells = S * S * S;
        for (int cb = 0; cb < Scells; cb += 64) {
            const int ci = cb + t;
            int cnt = 0, cstart = 0;
            if (ci < Scells) {
                const int dz = ci % S - R;
                const int dy = (ci / S) % S - R;
                const int dx = ci / (S * S) - R;
                int ax = dx < 0 ? -dx : dx, ay = dy < 0 ? -dy : dy, az = dz < 0 ? -dz : dz;
                int cheb = ax > ay ? ax : ay; if (az > cheb) cheb = az;
                const bool want = (R == 1) ? true : (cheb == R);   // R=1: full 27-cube
                const int X = cx + dx, Y = cy + dy, Z = cz + dz;
                if (want && X >= 0 && X < NC && Y >= 0 && Y < NC && Z >= 0 && Z < NC) {
                    const int cid = (X * NC + Y) * NC + Z;
                    cstart = coff[cid];
                    cnt = ccnt[cid];
                }
            }
            // wave inclusive scan of cnt
            int incl = cnt;
            for (int d = 1; d < 64; d <<= 1) {
                int v = __shfl_up(incl, d);
                if (t >= d) incl += v;
            }
            const int total = __shfl(incl, 63);
            const int pref = incl - cnt;
            c_start[t] = cstart; c_pref[t] = pref;
            __syncthreads();
            for (int pos = t; pos < total; pos += 64) {
                // rightmost slot with c_pref[slot] <= pos (binary search, 6 steps)
                int lo = 0, hi = 63;
                while (lo < hi) {
                    const int mid = (lo + hi + 1) >> 1;
                    if (c_pref[mid] <= pos) lo = mid; else hi = mid - 1;
                }
                const float4 cd = scell[c_start[lo] + (pos - c_pref[lo])];
                const double ddx = gx - (double)cd.x;
                const double ddy = gy - (double)cd.y;
                const double ddz = gz - (double)cd.z;
                const double d2 = ddx * ddx + ddy * ddy + ddz * ddz;
                const int sidx = __float_as_int(cd.w);
                if (d2 > bk[KK - 1]) continue;
                if (d2 == bk[KK - 1] && sidx > bi[KK - 1]) continue;
                double ck = d2; int ci2 = sidx;
#pragma unroll
                for (int j = 0; j < KK; ++j) {
                    const bool less = (ck < bk[j]) || (ck == bk[j] && ci2 < bi[j]);
                    const double nk = less ? ck : bk[j]; const int ni = less ? ci2 : bi[j];
                    const double ok = less ? bk[j] : ck; const int oi = less ? bi[j] : ci2;
                    bk[j] = nk; bi[j] = ni; ck = ok; ci2 = oi;
                }
            }
            __syncthreads();
        }
        // stop test: m = min distance from query to unexamined region
        double m = 1e300;
        if (cx - R > 0)      { double d = gx - (double)(cx - R) * 3.75; if (d < m) m = d; }
        if (cx + R < NC - 1) { double d = (double)(cx + R + 1) * 3.75 - gx; if (d < m) m = d; }
        if (cy - R > 0)      { double d = gy - (double)(cy - R) * 3.75; if (d < m) m = d; }
        if (cy + R < NC - 1) { double d = (double)(cy + R + 1) * 3.75 - gy; if (d < m) m = d; }
        if (cz - R > 0)      { double d = gz - (double)(cz - R) * 3.75; if (d < m) m = d; }
        if (cz + R < NC - 1) { double d = (double)(cz + R + 1) * 3.75 - gz; if (d < m) m = d; }
        if (m < 0.0) m = 0.0;
        const double m2 = m * m * (1.0 - 1e-12);
        int cntlt = 0;
#pragma unroll
        for (int j = 0; j < KK; ++j) cntlt += (bk[j] < m2) ? 1 : 0;
        for (int d = 1; d < 64; d <<= 1) cntlt += __shfl_xor(cntlt, d);
        if (cntlt >= KK) done = true;
    }

    // dump per-lane sorted lists, then 64-way merge (wave argmin extraction)
#pragma unroll
    for (int j = 0; j < KK; ++j) { skeys[t * KK + j] = bk[j]; ssidx[t * KK + j] = bi[j]; }
    __syncthreads();
    int h = 0;
    for (int p = 0; p < KK; ++p) {
        double key = (h < KK) ? skeys[t * KK + h] : 1e300;
        int    sid = (h < KK) ? ssidx[t * KK + h] : 0x7fffffff;
        for (int d = 1; d < 64; d <<= 1) {
            const double ok = __shfl_xor(key, d);
            const int    os = __shfl_xor(sid, d);
            if (ok < key || (ok == key && os < sid)) { key = ok; sid = os; }
        }
        if (t == 0) {
            idx_out[g * KK + p] = sid;
            w_out[g * KK + p] = expf((float)(-key) * (1.0f / 12.5f));
        }
        // advance the lane that owned the winner (unique by (key,sid) since sid unique)
        if (h < KK && skeys[t * KK + h] == key && ssidx[t * KK + h] == sid) ++h;
    }
}

// out[M x 128] = A[M x 128] @ W[128 x 128], f32 accumulate/out. 16 rows/block.
__global__ __launch_bounds__(128) void gemm_kernel(const void* A, const void* W,
                                                   float* __restrict__ out, int M) {
    __shared__ float a[16][DD];
    const int j = threadIdx.x;
    const int base = blockIdx.x * 16;
    const int bf = g_flag;
    for (int r = 0; r < 16; ++r) {
        const int row = base + r;
        a[r][j] = (row < M) ? ldIn(A, row * DD + j, bf) : 0.f;
    }
    __syncthreads();
    float acc[16];
#pragma unroll
    for (int r = 0; r < 16; ++r) acc[r] = 0.f;
    for (int i = 0; i < DD; ++i) {
        const float wv = ldIn(W, i * DD + j, bf);
#pragma unroll
        for (int r = 0; r < 16; ++r) acc[r] += a[r][i] * wv;
    }
    for (int r = 0; r < 16; ++r) {
        const int row = base + r;
        if (row < M) out[row * DD + j] = acc[r];
    }
}

// Wf[i][j] = sum_m W1[i][m] * Wp[128+m][j]  (fold message GEMM into post-GEMM)
__global__ __launch_bounds__(128) void wfuse_kernel(const void* W1, const void* Wp,
                                                    float* __restrict__ Wf) {
    __shared__ float row[DD];
    const int i = blockIdx.x, j = threadIdx.x, bf = g_flag;
    row[j] = ldIn(W1, i * DD + j, bf);
    __syncthreads();
    float acc = 0.f;
    for (int m = 0; m < DD; ++m) acc += row[m] * ldIn(Wp, (DD + m) * DD + j, bf);
    Wf[i * DD + j] = acc;
}

// ---- reverse-CSR build (graph->surface edges grouped by surface node) ----
__global__ void count_kernel(const int* __restrict__ idx, int* __restrict__ cnt) {
    const int e = blockIdx.x * 256 + threadIdx.x;
    if (e < NE) atomicAdd(&cnt[idx[e]], 1);
}
__global__ void fill_kernel(const int* __restrict__ idx, const float* __restrict__ w,
                            int* __restrict__ cur, int* __restrict__ rg,
                            float* __restrict__ rw) {
    const int e = blockIdx.x * 256 + threadIdx.x;
    if (e < NE) {
        const int s = idx[e];
        const int p = atomicAdd(&cur[s], 1);
        rg[p] = e >> 4;        // source graph node
        rw[p] = w[e];
    }
}

// out_s = relu(hs @ Wp_top + (sum_incoming w*hg[g]) @ Wfs), 16 rows/block.
__global__ __launch_bounds__(128) void final_s_kernel(
    const float* __restrict__ hs, const float* __restrict__ hg,
    const int* __restrict__ off, const int* __restrict__ cnt,
    const int* __restrict__ rg, const float* __restrict__ rw,
    const void* Wp, const float* __restrict__ wfs, void* out) {
    __shared__ float a1[16][DD];
    __shared__ float a2[16][DD];
    const int j = threadIdx.x;
    const int base = blockIdx.x * 16;
    const int bf = g_flag;
    for (int r = 0; r < 16; ++r) {
        const int row = base + r;
        a1[r][j] = hs[row * DD + j];
        float acc = 0.f;
        const int o = off[row], c = cnt[row];
        for (int e = 0; e < c; ++e) acc += rw[o + e] * hg[rg[o + e] * DD + j];
        a2[r][j] = acc;
    }
    __syncthreads();
    float acc[16];
#pragma unroll
    for (int r = 0; r < 16; ++r) acc[r] = 0.f;
    for (int i = 0; i < DD; ++i) {
        const float w1 = ldIn(Wp, i * DD + j, bf);
#pragma unroll
        for (int r = 0; r < 16; ++r) acc[r] += a1[r][i] * w1;
    }
    for (int i = 0; i < DD; ++i) {
        const float w2 = wfs[i * DD + j];
#pragma unroll
        for (int r = 0; r < 16; ++r) acc[r] += a2[r][i] * w2;
    }
    for (int r = 0; r < 16; ++r) {
        const int row = base + r;
        const float v = acc[r] > 0.f ? acc[r] : 0.f;
        stOut(out, row * DD + j, v, bf);
    }
}

// out_g = relu(hg @ Wp_top + (sum_k w*hs[idx]) @ Wfg) at element offset N_S*DD.
__global__ __launch_bounds__(128) void final_g_kernel(
    const float* __restrict__ hs, const float* __restrict__ hg,
    const int* __restrict__ idx, const float* __restrict__ w,
    const void* Wp, const float* __restrict__ wfg, void* out) {
    __shared__ float a1[16][DD];
    __shared__ float a2[16][DD];
    const int j = threadIdx.x;
    const int base = blockIdx.x * 16;
    const int bf = g_flag;
    for (int r = 0; r < 16; ++r) {
        const int row = base + r;
        if (row < N_G) {
            a1[r][j] = hg[row * DD + j];
            float acc = 0.f;
#pragma unroll
            for (int k = 0; k < KK; ++k)
                acc += w[row * KK + k] * hs[idx[row * KK + k] * DD + j];
            a2[r][j] = acc;
        } else { a1[r][j] = 0.f; a2[r][j] = 0.f; }
    }
    __syncthreads();
    float acc[16];
#pragma unroll
    for (int r = 0; r < 16; ++r) acc[r] = 0.f;
    for (int i = 0; i < DD; ++i) {
        const float w1 = ldIn(Wp, i * DD + j, bf);
#pragma unroll
        for (int r = 0; r < 16; ++r) acc[r] += a1[r][i] * w1;
    }
    for (int i = 0; i < DD; ++i) {
        const float w2 = wfg[i * DD + j];
#pragma unroll
        for (int r = 0; r < 16; ++r) acc[r] += a2[r][i] * w2;
    }
    for (int r = 0; r < 16; ++r) {
        const int row = base + r;
        if (row < N_G) {
            const float v = acc[r] > 0.f ? acc[r] : 0.f;
            stOut(out, N_S * DD + row * DD + j, v, bf);
        }
    }
}

extern "C" void kernel_launch(void* const* d_in, const int* in_sizes, int n_in,
                              void* d_out, int out_size, void* d_ws, size_t ws_size,
                              hipStream_t stream)
{
    const void* xs       = d_in[0];
    const void* xg       = d_in[1];
    const void* pos_s    = d_in[2];
    const void* pos_g    = d_in[3];
    const void* W_s_pre  = d_in[4];
    const void* W_g_pre  = d_in[5];
    const void* W_gs     = d_in[6];
    const void* W_sg     = d_in[7];
    const void* W_s_post = d_in[8];
    const void* W_g_post = d_in[9];
    (void)in_sizes; (void)n_in; (void)out_size; (void)ws_size;

    // scratch carve-out from d_ws (~19 MB)
    char* ws = (char*)d_ws;
    size_t off_b = 0;
    auto alloc = [&](size_t bytes) -> void* {
        void* p = ws + off_b;
        off_b = (off_b + bytes + 255) & ~((size_t)255);
        return p;
    };
    float*  hs    = (float*) alloc((size_t)N_S * DD * 4);
    float*  hg    = (float*) alloc((size_t)N_G * DD * 4);
    float*  wfs   = (float*) alloc((size_t)DD * DD * 4);
    float*  wfg   = (float*) alloc((size_t)DD * DD * 4);
    int*    idx   = (int*)   alloc((size_t)NE * 4);
    float*  w     = (float*) alloc((size_t)NE * 4);
    int*    cnt   = (int*)   alloc((size_t)N_S * 4);
    int*    offs  = (int*)   alloc((size_t)N_S * 4);
    int*    cur   = (int*)   alloc((size_t)N_S * 4);
    int*    rg    = (int*)   alloc((size_t)NE * 4);
    float*  rw    = (float*) alloc((size_t)NE * 4);
    int*    ccnt  = (int*)   alloc((size_t)CELLS * 4);
    int*    coff  = (int*)   alloc((size_t)CELLS * 4);
    int*    ccur  = (int*)   alloc((size_t)CELLS * 4);
    float4* scell = (float4*)alloc((size_t)N_S * 16);

    detect_kernel<<<1, 256, 0, stream>>>(pos_g);

    // build surface-point grid CSR
    zero_kernel<<<(CELLS + 255) / 256, 256, 0, stream>>>(ccnt, CELLS);
    cell_count_kernel<<<(N_S + 255) / 256, 256, 0, stream>>>(pos_s, ccnt);
    scan_kernel<<<1, 256, 0, stream>>>(ccnt, coff, ccur, CELLS);
    cell_fill_kernel<<<(N_S + 255) / 256, 256, 0, stream>>>(pos_s, ccur, scell);

    knn_grid_kernel<<<N_G, 64, 0, stream>>>(pos_g, coff, ccnt, scell, idx, w);

    gemm_kernel<<<(N_S + 15) / 16, 128, 0, stream>>>(xs, W_s_pre, hs, N_S);
    gemm_kernel<<<(N_G + 15) / 16, 128, 0, stream>>>(xg, W_g_pre, hg, N_G);

    zero_kernel<<<(N_S + 255) / 256, 256, 0, stream>>>(cnt, N_S);
    count_kernel<<<(NE + 255) / 256, 256, 0, stream>>>(idx, cnt);
    scan_kernel<<<1, 256, 0, stream>>>(cnt, offs, cur, N_S);
    fill_kernel<<<(NE + 255) / 256, 256, 0, stream>>>(idx, w, cur, rg, rw);
    wfuse_kernel<<<DD, DD, 0, stream>>>(W_gs, W_s_post, wfs);
    wfuse_kernel<<<DD, DD, 0, stream>>>(W_sg, W_g_post, wfg);
    final_s_kernel<<<N_S / 16, 128, 0, stream>>>(hs, hg, offs, cnt, rg, rw,
                                                 W_s_post, wfs, d_out);
    final_g_kernel<<<(N_G + 15) / 16, 128, 0, stream>>>(hs, hg, idx, w,
                                                        W_g_post, wfg, d_out);
}

// Round 5
// 397.315 us; speedup vs baseline: 4.0906x; 1.2948x over previous
//
#include <hip/hip_runtime.h>
#include <stdint.h>

#define N_S 30000
#define N_G 3000
#define DD  128
#define KK  16
#define NE  (N_G * KK)
#define NC  16            // cells per axis
#define CELLS (NC * NC * NC)
#define CH  3.75f         // cell size (60/16), exactly representable

// Only device-side-accessed global state (never passed as a kernel arg from host).
__device__ int g_flag;   // 1 = tensors are bf16, 0 = f32

__device__ __forceinline__ float bf2f(unsigned short u) {
    union { unsigned int i; float f; } v; v.i = ((unsigned int)u) << 16; return v.f;
}
__device__ __forceinline__ unsigned short f2bf(float f) {
    union { float f; unsigned int i; } v; v.f = f;
    unsigned int x = v.i;
    return (unsigned short)((x + 0x7fffu + ((x >> 16) & 1u)) >> 16);
}
__device__ __forceinline__ float ldIn(const void* p, int i, int bf) {
    return bf ? bf2f(((const unsigned short*)p)[i]) : ((const float*)p)[i];
}
__device__ __forceinline__ void stOut(void* p, int i, float v, int bf) {
    if (bf) ((unsigned short*)p)[i] = f2bf(v);
    else    ((float*)p)[i] = v;
}
__device__ __forceinline__ int cellOf(float x) {
    int c = (int)(x * (1.0f / CH));
    if (c < 0) c = 0; if (c > NC - 1) c = NC - 1;
    return c;
}

// dtype detection + ccnt zeroing (fused; both trivially small).
__global__ void detect_kernel(const void* pos_g, int* __restrict__ ccnt) {
    const unsigned int* w = (const unsigned int*)pos_g;
    __shared__ int sv[256];
    const int t = threadIdx.x;
    for (int i = t; i < CELLS; i += 256) ccnt[i] = 0;
    int votes = 0;
    for (int i = t; i < 4500; i += 256) {
        unsigned int b = (w[i] >> 8) & 0xFFu;
        if (b >= 0x3Eu && b <= 0x42u) votes++;
    }
    sv[t] = votes; __syncthreads();
    for (int o = 128; o > 0; o >>= 1) {
        if (t < o) sv[t] += sv[t + o];
        __syncthreads();
    }
    if (t == 0) g_flag = (sv[0] > 2250) ? 1 : 0;
}

__global__ void cell_count_kernel(const void* pos_s, int* __restrict__ ccnt) {
    const int p = blockIdx.x * 256 + threadIdx.x;
    if (p < N_S) {
        const int bf = g_flag;
        const int cx = cellOf(ldIn(pos_s, 3 * p + 0, bf));
        const int cy = cellOf(ldIn(pos_s, 3 * p + 1, bf));
        const int cz = cellOf(ldIn(pos_s, 3 * p + 2, bf));
        atomicAdd(&ccnt[(cx * NC + cy) * NC + cz], 1);
    }
}

// exclusive scan of exactly CELLS=4096 ints: 1024 threads, 4 elems/thread.
__global__ __launch_bounds__(1024) void cell_scan_kernel(
    const int* __restrict__ cnt, int* __restrict__ off, int* __restrict__ cur) {
    __shared__ int part[1024];
    const int t = threadIdx.x;
    const int v0 = cnt[4 * t + 0], v1 = cnt[4 * t + 1];
    const int v2 = cnt[4 * t + 2], v3 = cnt[4 * t + 3];
    const int s = v0 + v1 + v2 + v3;
    part[t] = s;
    __syncthreads();
    for (int o = 1; o < 1024; o <<= 1) {
        const int x = (t >= o) ? part[t - o] : 0;
        __syncthreads();
        part[t] += x;
        __syncthreads();
    }
    const int base = part[t] - s;   // exclusive
    const int e0 = base, e1 = base + v0, e2 = base + v0 + v1, e3 = base + v0 + v1 + v2;
    off[4 * t + 0] = e0; cur[4 * t + 0] = e0;
    off[4 * t + 1] = e1; cur[4 * t + 1] = e1;
    off[4 * t + 2] = e2; cur[4 * t + 2] = e2;
    off[4 * t + 3] = e3; cur[4 * t + 3] = e3;
}

__global__ void cell_fill_kernel(const void* pos_s, int* __restrict__ ccur,
                                 float4* __restrict__ scell) {
    const int p = blockIdx.x * 256 + threadIdx.x;
    if (p < N_S) {
        const int bf = g_flag;
        const float x = ldIn(pos_s, 3 * p + 0, bf);
        const float y = ldIn(pos_s, 3 * p + 1, bf);
        const float z = ldIn(pos_s, 3 * p + 2, bf);
        const int cid = (cellOf(x) * NC + cellOf(y)) * NC + cellOf(z);
        const int slot = atomicAdd(&ccur[cid], 1);
        scell[slot] = make_float4(x, y, z, __int_as_float(p));
    }
}

// ---------------------------------------------------------------------------
// Grid-accelerated exact kNN. One 64-thread block (one wave) per graph node.
// f64 distances (exact for bf16/f32-origin coords), lower-index tie-break.
// Shell expansion with conservative stop rule => identical result to brute force.
// ---------------------------------------------------------------------------
__global__ __launch_bounds__(64) void knn_grid_kernel(
    const void* pos_g,
    const int* __restrict__ coff, const int* __restrict__ ccnt,
    const float4* __restrict__ scell,
    int* __restrict__ idx_out, float* __restrict__ w_out)
{
    __shared__ int    c_start[64];
    __shared__ int    c_pref[64];
    __shared__ double skeys[64 * KK];
    __shared__ int    ssidx[64 * KK];

    const int g = blockIdx.x;
    const int t = threadIdx.x;
    const int bf = g_flag;

    const float gxf = ldIn(pos_g, 3 * g + 0, bf);
    const float gyf = ldIn(pos_g, 3 * g + 1, bf);
    const float gzf = ldIn(pos_g, 3 * g + 2, bf);
    const double gx = (double)gxf, gy = (double)gyf, gz = (double)gzf;
    const int cx = cellOf(gxf), cy = cellOf(gyf), cz = cellOf(gzf);

    double bk[KK]; int bi[KK];
#pragma unroll
    for (int j = 0; j < KK; ++j) { bk[j] = 1e300; bi[j] = 0x7fffffff; }

    bool done = false;
    for (int R = 1; R <= NC && !done; ++R) {
        const int S = 2 * R + 1;
        const int Scells = S * S * S;
        for (int cb = 0; cb < Scells; cb += 64) {
            const int ci = cb + t;
            int cnt = 0, cstart = 0;
            if (ci < Scells) {
                const int dz = ci % S - R;
                const int dy = (ci / S) % S - R;
                const int dx = ci / (S * S) - R;
                int ax = dx < 0 ? -dx : dx, ay = dy < 0 ? -dy : dy, az = dz < 0 ? -dz : dz;
                int cheb = ax > ay ? ax : ay; if (az > cheb) cheb = az;
                const bool want = (R == 1) ? true : (cheb == R);   // R=1: full 27-cube
                const int X = cx + dx, Y = cy + dy, Z = cz + dz;
                if (want && X >= 0 && X < NC && Y >= 0 && Y < NC && Z >= 0 && Z < NC) {
                    const int cid = (X * NC + Y) * NC + Z;
                    cstart = coff[cid];
                    cnt = ccnt[cid];
                }
            }
            // wave inclusive scan of cnt
            int incl = cnt;
            for (int d = 1; d < 64; d <<= 1) {
                int v = __shfl_up(incl, d);
                if (t >= d) incl += v;
            }
            const int total = __shfl(incl, 63);
            const int pref = incl - cnt;
            c_start[t] = cstart; c_pref[t] = pref;
            __syncthreads();
            for (int pos = t; pos < total; pos += 64) {
                // rightmost slot with c_pref[slot] <= pos (binary search, 6 steps)
                int lo = 0, hi = 63;
                while (lo < hi) {
                    const int mid = (lo + hi + 1) >> 1;
                    if (c_pref[mid] <= pos) lo = mid; else hi = mid - 1;
                }
                const float4 cd = scell[c_start[lo] + (pos - c_pref[lo])];
                const double ddx = gx - (double)cd.x;
                const double ddy = gy - (double)cd.y;
                const double ddz = gz - (double)cd.z;
                const double d2 = ddx * ddx + ddy * ddy + ddz * ddz;
                const int sidx = __float_as_int(cd.w);
                if (d2 > bk[KK - 1]) continue;
                if (d2 == bk[KK - 1] && sidx > bi[KK - 1]) continue;
                double ck = d2; int ci2 = sidx;
#pragma unroll
                for (int j = 0; j < KK; ++j) {
                    const bool less = (ck < bk[j]) || (ck == bk[j] && ci2 < bi[j]);
                    const double nk = less ? ck : bk[j]; const int ni = less ? ci2 : bi[j];
                    const double ok = less ? bk[j] : ck; const int oi = less ? bi[j] : ci2;
                    bk[j] = nk; bi[j] = ni; ck = ok; ci2 = oi;
                }
            }
            __syncthreads();
        }
        // stop test: m = min distance from query to unexamined region
        double m = 1e300;
        if (cx - R > 0)      { double d = gx - (double)(cx - R) * 3.75; if (d < m) m = d; }
        if (cx + R < NC - 1) { double d = (double)(cx + R + 1) * 3.75 - gx; if (d < m) m = d; }
        if (cy - R > 0)      { double d = gy - (double)(cy - R) * 3.75; if (d < m) m = d; }
        if (cy + R < NC - 1) { double d = (double)(cy + R + 1) * 3.75 - gy; if (d < m) m = d; }
        if (cz - R > 0)      { double d = gz - (double)(cz - R) * 3.75; if (d < m) m = d; }
        if (cz + R < NC - 1) { double d = (double)(cz + R + 1) * 3.75 - gz; if (d < m) m = d; }
        if (m < 0.0) m = 0.0;
        const double m2 = m * m * (1.0 - 1e-12);
        int cntlt = 0;
#pragma unroll
        for (int j = 0; j < KK; ++j) cntlt += (bk[j] < m2) ? 1 : 0;
        for (int d = 1; d < 64; d <<= 1) cntlt += __shfl_xor(cntlt, d);
        if (cntlt >= KK) done = true;
    }

    // dump per-lane sorted lists, then 64-way merge (wave argmin extraction)
#pragma unroll
    for (int j = 0; j < KK; ++j) { skeys[t * KK + j] = bk[j]; ssidx[t * KK + j] = bi[j]; }
    __syncthreads();
    int h = 0;
    for (int p = 0; p < KK; ++p) {
        double key = (h < KK) ? skeys[t * KK + h] : 1e300;
        int    sid = (h < KK) ? ssidx[t * KK + h] : 0x7fffffff;
        for (int d = 1; d < 64; d <<= 1) {
            const double ok = __shfl_xor(key, d);
            const int    os = __shfl_xor(sid, d);
            if (ok < key || (ok == key && os < sid)) { key = ok; sid = os; }
        }
        if (t == 0) {
            idx_out[g * KK + p] = sid;
            w_out[g * KK + p] = expf((float)(-key) * (1.0f / 12.5f));
        }
        // advance the lane that owned the winner (unique by (key,sid) since sid unique)
        if (h < KK && skeys[t * KK + h] == key && ssidx[t * KK + h] == sid) ++h;
    }
}

// out[M x 128] = A[M x 128] @ W[128 x 128], f32 accumulate/out. 16 rows/block.
__global__ __launch_bounds__(128) void gemm_kernel(const void* A, const void* W,
                                                   float* __restrict__ out, int M) {
    __shared__ float a[16][DD];
    const int j = threadIdx.x;
    const int base = blockIdx.x * 16;
    const int bf = g_flag;
    for (int r = 0; r < 16; ++r) {
        const int row = base + r;
        a[r][j] = (row < M) ? ldIn(A, row * DD + j, bf) : 0.f;
    }
    __syncthreads();
    float acc[16];
#pragma unroll
    for (int r = 0; r < 16; ++r) acc[r] = 0.f;
    for (int i = 0; i < DD; ++i) {
        const float wv = ldIn(W, i * DD + j, bf);
#pragma unroll
        for (int r = 0; r < 16; ++r) acc[r] += a[r][i] * wv;
    }
    for (int r = 0; r < 16; ++r) {
        const int row = base + r;
        if (row < M) out[row * DD + j] = acc[r];
    }
}

// Wf[i][j] = sum_m W1[i][m] * Wp[128+m][j]  (fold message GEMM into post-GEMM)
__global__ __launch_bounds__(128) void wfuse_kernel(const void* W1, const void* Wp,
                                                    float* __restrict__ Wf) {
    __shared__ float row[DD];
    const int i = blockIdx.x, j = threadIdx.x, bf = g_flag;
    row[j] = ldIn(W1, i * DD + j, bf);
    __syncthreads();
    float acc = 0.f;
    for (int m = 0; m < DD; ++m) acc += row[m] * ldIn(Wp, (DD + m) * DD + j, bf);
    Wf[i * DD + j] = acc;
}

// xs_agg[idx[g,k]] += w[g,k] * hg[g]   (f32 atomics, coalesced per wave)
__global__ __launch_bounds__(128) void scatter_kernel(
    const float* __restrict__ hg, const int* __restrict__ idx,
    const float* __restrict__ w, float* __restrict__ xs_agg) {
    const int g = blockIdx.x;
    const int j = threadIdx.x;
    const float m = hg[g * DD + j];
#pragma unroll
    for (int k = 0; k < KK; ++k) {
        const int s = idx[g * KK + k];
        const float wt = w[g * KK + k];
        atomicAdd(&xs_agg[s * DD + j], m * wt);
    }
}

// out_s = relu(hs @ Wp_top + xs_agg @ Wfs), 16 rows/block.
__global__ __launch_bounds__(128) void final_s_kernel(
    const float* __restrict__ hs, const float* __restrict__ xs_agg,
    const void* Wp, const float* __restrict__ wfs, void* out) {
    __shared__ float a1[16][DD];
    __shared__ float a2[16][DD];
    const int j = threadIdx.x;
    const int base = blockIdx.x * 16;
    const int bf = g_flag;
    for (int r = 0; r < 16; ++r) {
        const int row = base + r;
        a1[r][j] = hs[row * DD + j];
        a2[r][j] = xs_agg[row * DD + j];
    }
    __syncthreads();
    float acc[16];
#pragma unroll
    for (int r = 0; r < 16; ++r) acc[r] = 0.f;
    for (int i = 0; i < DD; ++i) {
        const float w1 = ldIn(Wp, i * DD + j, bf);
#pragma unroll
        for (int r = 0; r < 16; ++r) acc[r] += a1[r][i] * w1;
    }
    for (int i = 0; i < DD; ++i) {
        const float w2 = wfs[i * DD + j];
#pragma unroll
        for (int r = 0; r < 16; ++r) acc[r] += a2[r][i] * w2;
    }
    for (int r = 0; r < 16; ++r) {
        const int row = base + r;
        const float v = acc[r] > 0.f ? acc[r] : 0.f;
        stOut(out, row * DD + j, v, bf);
    }
}

// out_g = relu(hg @ Wp_top + (sum_k w*hs[idx]) @ Wfg) at element offset N_S*DD.
__global__ __launch_bounds__(128) void final_g_kernel(
    const float* __restrict__ hs, const float* __restrict__ hg,
    const int* __restrict__ idx, const float* __restrict__ w,
    const void* Wp, const float* __restrict__ wfg, void* out) {
    __shared__ float a1[16][DD];
    __shared__ float a2[16][DD];
    const int j = threadIdx.x;
    const int base = blockIdx.x * 16;
    const int bf = g_flag;
    for (int r = 0; r < 16; ++r) {
        const int row = base + r;
        if (row < N_G) {
            a1[r][j] = hg[row * DD + j];
            float acc = 0.f;
#pragma unroll
            for (int k = 0; k < KK; ++k)
                acc += w[row * KK + k] * hs[idx[row * KK + k] * DD + j];
            a2[r][j] = acc;
        } else { a1[r][j] = 0.f; a2[r][j] = 0.f; }
    }
    __syncthreads();
    float acc[16];
#pragma unroll
    for (int r = 0; r < 16; ++r) acc[r] = 0.f;
    for (int i = 0; i < DD; ++i) {
        const float w1 = ldIn(Wp, i * DD + j, bf);
#pragma unroll
        for (int r = 0; r < 16; ++r) acc[r] += a1[r][i] * w1;
    }
    for (int i = 0; i < DD; ++i) {
        const float w2 = wfg[i * DD + j];
#pragma unroll
        for (int r = 0; r < 16; ++r) acc[r] += a2[r][i] * w2;
    }
    for (int r = 0; r < 16; ++r) {
        const int row = base + r;
        if (row < N_G) {
            const float v = acc[r] > 0.f ? acc[r] : 0.f;
            stOut(out, N_S * DD + row * DD + j, v, bf);
        }
    }
}

extern "C" void kernel_launch(void* const* d_in, const int* in_sizes, int n_in,
                              void* d_out, int out_size, void* d_ws, size_t ws_size,
                              hipStream_t stream)
{
    const void* xs       = d_in[0];
    const void* xg       = d_in[1];
    const void* pos_s    = d_in[2];
    const void* pos_g    = d_in[3];
    const void* W_s_pre  = d_in[4];
    const void* W_g_pre  = d_in[5];
    const void* W_gs     = d_in[6];
    const void* W_sg     = d_in[7];
    const void* W_s_post = d_in[8];
    const void* W_g_post = d_in[9];
    (void)in_sizes; (void)n_in; (void)out_size; (void)ws_size;

    // scratch carve-out from d_ws (~31.8 MiB; round-1 demonstrated >= ~32.6 MiB usable)
    char* ws = (char*)d_ws;
    size_t off_b = 0;
    auto alloc = [&](size_t bytes) -> void* {
        void* p = ws + off_b;
        off_b = (off_b + bytes + 255) & ~((size_t)255);
        return p;
    };
    float*  hs     = (float*) alloc((size_t)N_S * DD * 4);
    float*  hg     = (float*) alloc((size_t)N_G * DD * 4);
    float*  xs_agg = (float*) alloc((size_t)N_S * DD * 4);
    float*  wfs    = (float*) alloc((size_t)DD * DD * 4);
    float*  wfg    = (float*) alloc((size_t)DD * DD * 4);
    int*    idx    = (int*)   alloc((size_t)NE * 4);
    float*  w      = (float*) alloc((size_t)NE * 4);
    int*    ccnt   = (int*)   alloc((size_t)CELLS * 4);
    int*    coff   = (int*)   alloc((size_t)CELLS * 4);
    int*    ccur   = (int*)   alloc((size_t)CELLS * 4);
    float4* scell  = (float4*)alloc((size_t)N_S * 16);

    hipMemsetAsync(xs_agg, 0, (size_t)N_S * DD * 4, stream);

    detect_kernel<<<1, 256, 0, stream>>>(pos_g, ccnt);

    // build surface-point grid CSR
    cell_count_kernel<<<(N_S + 255) / 256, 256, 0, stream>>>(pos_s, ccnt);
    cell_scan_kernel<<<1, 1024, 0, stream>>>(ccnt, coff, ccur);
    cell_fill_kernel<<<(N_S + 255) / 256, 256, 0, stream>>>(pos_s, ccur, scell);

    knn_grid_kernel<<<N_G, 64, 0, stream>>>(pos_g, coff, ccnt, scell, idx, w);

    gemm_kernel<<<(N_S + 15) / 16, 128, 0, stream>>>(xs, W_s_pre, hs, N_S);
    gemm_kernel<<<(N_G + 15) / 16, 128, 0, stream>>>(xg, W_g_pre, hg, N_G);

    scatter_kernel<<<N_G, 128, 0, stream>>>(hg, idx, w, xs_agg);

    wfuse_kernel<<<DD, DD, 0, stream>>>(W_gs, W_s_post, wfs);
    wfuse_kernel<<<DD, DD, 0, stream>>>(W_sg, W_g_post, wfg);

    final_s_kernel<<<N_S / 16, 128, 0, stream>>>(hs, xs_agg, W_s_post, wfs, d_out);
    final_g_kernel<<<(N_G + 15) / 16, 128, 0, stream>>>(hs, hg, idx, w,
                                                        W_g_post, wfg, d_out);
}

// Round 6
// 256.995 us; speedup vs baseline: 6.3241x; 1.5460x over previous
//
#include <hip/hip_runtime.h>
#include <stdint.h>

#define N_S 30000
#define N_G 3000
#define DD  128
#define KK  16
#define NE  (N_G * KK)
#define NC  16            // cells per axis
#define CELLS (NC * NC * NC)
#define CH  3.75f         // cell size (60/16), exactly representable

using v8s = __attribute__((ext_vector_type(8))) short;   // 8 bf16 (4 VGPRs)
using v4f = __attribute__((ext_vector_type(4))) float;   // MFMA accumulator

// Only device-side-accessed global state (never passed as a kernel arg from host).
__device__ int g_flag;   // 1 = tensors are bf16, 0 = f32

__device__ __forceinline__ float bf2f(unsigned short u) {
    union { unsigned int i; float f; } v; v.i = ((unsigned int)u) << 16; return v.f;
}
__device__ __forceinline__ unsigned short f2bf(float f) {
    union { float f; unsigned int i; } v; v.f = f;
    unsigned int x = v.i;
    return (unsigned short)((x + 0x7fffu + ((x >> 16) & 1u)) >> 16);
}
__device__ __forceinline__ float ldIn(const void* p, int i, int bf) {
    return bf ? bf2f(((const unsigned short*)p)[i]) : ((const float*)p)[i];
}
__device__ __forceinline__ void stOut(void* p, int i, float v, int bf) {
    if (bf) ((unsigned short*)p)[i] = f2bf(v);
    else    ((float*)p)[i] = v;
}
__device__ __forceinline__ int cellOf(float x) {
    int c = (int)(x * (1.0f / CH));
    if (c < 0) c = 0; if (c > NC - 1) c = NC - 1;
    return c;
}

// dtype detection + ccnt zeroing (fused; both trivially small).
__global__ void detect_kernel(const void* pos_g, int* __restrict__ ccnt) {
    const unsigned int* w = (const unsigned int*)pos_g;
    __shared__ int sv[256];
    const int t = threadIdx.x;
    for (int i = t; i < CELLS; i += 256) ccnt[i] = 0;
    int votes = 0;
    for (int i = t; i < 4500; i += 256) {
        unsigned int b = (w[i] >> 8) & 0xFFu;
        if (b >= 0x3Eu && b <= 0x42u) votes++;
    }
    sv[t] = votes; __syncthreads();
    for (int o = 128; o > 0; o >>= 1) {
        if (t < o) sv[t] += sv[t + o];
        __syncthreads();
    }
    if (t == 0) g_flag = (sv[0] > 2250) ? 1 : 0;
}

__global__ void cell_count_kernel(const void* pos_s, int* __restrict__ ccnt) {
    const int p = blockIdx.x * 256 + threadIdx.x;
    if (p < N_S) {
        const int bf = g_flag;
        const int cx = cellOf(ldIn(pos_s, 3 * p + 0, bf));
        const int cy = cellOf(ldIn(pos_s, 3 * p + 1, bf));
        const int cz = cellOf(ldIn(pos_s, 3 * p + 2, bf));
        atomicAdd(&ccnt[(cx * NC + cy) * NC + cz], 1);
    }
}

// exclusive scan of exactly CELLS=4096 ints: 1024 threads, 4 elems/thread.
__global__ __launch_bounds__(1024) void cell_scan_kernel(
    const int* __restrict__ cnt, int* __restrict__ off, int* __restrict__ cur) {
    __shared__ int part[1024];
    const int t = threadIdx.x;
    const int v0 = cnt[4 * t + 0], v1 = cnt[4 * t + 1];
    const int v2 = cnt[4 * t + 2], v3 = cnt[4 * t + 3];
    const int s = v0 + v1 + v2 + v3;
    part[t] = s;
    __syncthreads();
    for (int o = 1; o < 1024; o <<= 1) {
        const int x = (t >= o) ? part[t - o] : 0;
        __syncthreads();
        part[t] += x;
        __syncthreads();
    }
    const int base = part[t] - s;   // exclusive
    const int e0 = base, e1 = base + v0, e2 = base + v0 + v1, e3 = base + v0 + v1 + v2;
    off[4 * t + 0] = e0; cur[4 * t + 0] = e0;
    off[4 * t + 1] = e1; cur[4 * t + 1] = e1;
    off[4 * t + 2] = e2; cur[4 * t + 2] = e2;
    off[4 * t + 3] = e3; cur[4 * t + 3] = e3;
}

__global__ void cell_fill_kernel(const void* pos_s, int* __restrict__ ccur,
                                 float4* __restrict__ scell) {
    const int p = blockIdx.x * 256 + threadIdx.x;
    if (p < N_S) {
        const int bf = g_flag;
        const float x = ldIn(pos_s, 3 * p + 0, bf);
        const float y = ldIn(pos_s, 3 * p + 1, bf);
        const float z = ldIn(pos_s, 3 * p + 2, bf);
        const int cid = (cellOf(x) * NC + cellOf(y)) * NC + cellOf(z);
        const int slot = atomicAdd(&ccur[cid], 1);
        scell[slot] = make_float4(x, y, z, __int_as_float(p));
    }
}

// ---------------------------------------------------------------------------
// Grid-accelerated exact kNN. One 64-thread block (one wave) per graph node.
// f64 distances (exact for bf16/f32-origin coords), lower-index tie-break.
// ---------------------------------------------------------------------------
__global__ __launch_bounds__(64) void knn_grid_kernel(
    const void* pos_g,
    const int* __restrict__ coff, const int* __restrict__ ccnt,
    const float4* __restrict__ scell,
    int* __restrict__ idx_out, float* __restrict__ w_out)
{
    __shared__ int    c_start[64];
    __shared__ int    c_pref[64];
    __shared__ double skeys[64 * KK];
    __shared__ int    ssidx[64 * KK];

    const int g = blockIdx.x;
    const int t = threadIdx.x;
    const int bf = g_flag;

    const float gxf = ldIn(pos_g, 3 * g + 0, bf);
    const float gyf = ldIn(pos_g, 3 * g + 1, bf);
    const float gzf = ldIn(pos_g, 3 * g + 2, bf);
    const double gx = (double)gxf, gy = (double)gyf, gz = (double)gzf;
    const int cx = cellOf(gxf), cy = cellOf(gyf), cz = cellOf(gzf);

    double bk[KK]; int bi[KK];
#pragma unroll
    for (int j = 0; j < KK; ++j) { bk[j] = 1e300; bi[j] = 0x7fffffff; }

    bool done = false;
    for (int R = 1; R <= NC && !done; ++R) {
        const int S = 2 * R + 1;
        const int Scells = S * S * S;
        for (int cb = 0; cb < Scells; cb += 64) {
            const int ci = cb + t;
            int cnt = 0, cstart = 0;
            if (ci < Scells) {
                const int dz = ci % S - R;
                const int dy = (ci / S) % S - R;
                const int dx = ci / (S * S) - R;
                int ax = dx < 0 ? -dx : dx, ay = dy < 0 ? -dy : dy, az = dz < 0 ? -dz : dz;
                int cheb = ax > ay ? ax : ay; if (az > cheb) cheb = az;
                const bool want = (R == 1) ? true : (cheb == R);
                const int X = cx + dx, Y = cy + dy, Z = cz + dz;
                if (want && X >= 0 && X < NC && Y >= 0 && Y < NC && Z >= 0 && Z < NC) {
                    const int cid = (X * NC + Y) * NC + Z;
                    cstart = coff[cid];
                    cnt = ccnt[cid];
                }
            }
            int incl = cnt;
            for (int d = 1; d < 64; d <<= 1) {
                int v = __shfl_up(incl, d);
                if (t >= d) incl += v;
            }
            const int total = __shfl(incl, 63);
            const int pref = incl - cnt;
            c_start[t] = cstart; c_pref[t] = pref;
            __syncthreads();
            for (int pos = t; pos < total; pos += 64) {
                int lo = 0, hi = 63;
                while (lo < hi) {
                    const int mid = (lo + hi + 1) >> 1;
                    if (c_pref[mid] <= pos) lo = mid; else hi = mid - 1;
                }
                const float4 cd = scell[c_start[lo] + (pos - c_pref[lo])];
                const double ddx = gx - (double)cd.x;
                const double ddy = gy - (double)cd.y;
                const double ddz = gz - (double)cd.z;
                const double d2 = ddx * ddx + ddy * ddy + ddz * ddz;
                const int sidx = __float_as_int(cd.w);
                if (d2 > bk[KK - 1]) continue;
                if (d2 == bk[KK - 1] && sidx > bi[KK - 1]) continue;
                double ck = d2; int ci2 = sidx;
#pragma unroll
                for (int j = 0; j < KK; ++j) {
                    const bool less = (ck < bk[j]) || (ck == bk[j] && ci2 < bi[j]);
                    const double nk = less ? ck : bk[j]; const int ni = less ? ci2 : bi[j];
                    const double ok = less ? bk[j] : ck; const int oi = less ? bi[j] : ci2;
                    bk[j] = nk; bi[j] = ni; ck = ok; ci2 = oi;
                }
            }
            __syncthreads();
        }
        double m = 1e300;
        if (cx - R > 0)      { double d = gx - (double)(cx - R) * 3.75; if (d < m) m = d; }
        if (cx + R < NC - 1) { double d = (double)(cx + R + 1) * 3.75 - gx; if (d < m) m = d; }
        if (cy - R > 0)      { double d = gy - (double)(cy - R) * 3.75; if (d < m) m = d; }
        if (cy + R < NC - 1) { double d = (double)(cy + R + 1) * 3.75 - gy; if (d < m) m = d; }
        if (cz - R > 0)      { double d = gz - (double)(cz - R) * 3.75; if (d < m) m = d; }
        if (cz + R < NC - 1) { double d = (double)(cz + R + 1) * 3.75 - gz; if (d < m) m = d; }
        if (m < 0.0) m = 0.0;
        const double m2 = m * m * (1.0 - 1e-12);
        int cntlt = 0;
#pragma unroll
        for (int j = 0; j < KK; ++j) cntlt += (bk[j] < m2) ? 1 : 0;
        for (int d = 1; d < 64; d <<= 1) cntlt += __shfl_xor(cntlt, d);
        if (cntlt >= KK) done = true;
    }

#pragma unroll
    for (int j = 0; j < KK; ++j) { skeys[t * KK + j] = bk[j]; ssidx[t * KK + j] = bi[j]; }
    __syncthreads();
    int h = 0;
    for (int p = 0; p < KK; ++p) {
        double key = (h < KK) ? skeys[t * KK + h] : 1e300;
        int    sid = (h < KK) ? ssidx[t * KK + h] : 0x7fffffff;
        for (int d = 1; d < 64; d <<= 1) {
            const double ok = __shfl_xor(key, d);
            const int    os = __shfl_xor(sid, d);
            if (ok < key || (ok == key && os < sid)) { key = ok; sid = os; }
        }
        if (t == 0) {
            idx_out[g * KK + p] = sid;
            w_out[g * KK + p] = expf((float)(-key) * (1.0f / 12.5f));
        }
        if (h < KK && skeys[t * KK + h] == key && ssidx[t * KK + h] == sid) ++h;
    }
}

// ---------------------------------------------------------------------------
// Weight packing into MFMA B-fragment order:
// element (k,n) -> wpk[((ks*4+q)*128 + n)*8 + i],  k = ks*32 + q*8 + i.
// Lane (quad q, n=lane&15) then loads 16 contiguous bytes per fragment.
// ---------------------------------------------------------------------------
__global__ void pack_w_kernel(const void* W, unsigned short* __restrict__ wpk, int K) {
    const int id = blockIdx.x * 256 + threadIdx.x;
    if (id < K * 128) {
        const int k = id / 128, n = id % 128;
        const int ks = k >> 5, q = (k >> 3) & 3, i = k & 7;
        wpk[((ks * 4 + q) * 128 + n) * 8 + i] = f2bf(ldIn(W, id, g_flag));
    }
}

// Wf (f32) = W1 @ Wp[128:256]  — fold message GEMM into the post GEMM.
__global__ __launch_bounds__(128) void wfuse_kernel(const void* W1, const void* Wp,
                                                    float* __restrict__ Wf) {
    __shared__ float row[DD];
    const int i = blockIdx.x, j = threadIdx.x, bf = g_flag;
    row[j] = ldIn(W1, i * DD + j, bf);
    __syncthreads();
    float acc = 0.f;
    for (int m = 0; m < DD; ++m) acc += row[m] * ldIn(Wp, (DD + m) * DD + j, bf);
    Wf[i * DD + j] = acc;
}

// Pack the 256x128 combined weight (top = Wp rows 0..127, bottom = Wf f32).
__global__ void pack_wc_kernel(const void* Wp, const float* __restrict__ wf,
                               unsigned short* __restrict__ wpk) {
    const int id = blockIdx.x * 256 + threadIdx.x;
    if (id < 256 * 128) {
        const int k = id / 128, n = id % 128;
        const float v = (k < 128) ? ldIn(Wp, k * 128 + n, g_flag) : wf[(k - 128) * 128 + n];
        const int ks = k >> 5, q = (k >> 3) & 3, i = k & 7;
        wpk[((ks * 4 + q) * 128 + n) * 8 + i] = f2bf(v);
    }
}

// A-fragment load: mode 0 = bf16 ptr, 1 = f32 ptr, 2 = raw input (dtype per bf).
__device__ __forceinline__ v8s loadA(const void* A, size_t off, int mode, int bf) {
    if (mode == 0 || (mode == 2 && bf)) {
        return *(const v8s*)((const unsigned short*)A + off);
    }
    const float* f = (const float*)A + off;
    v8s r;
#pragma unroll
    for (int i = 0; i < 8; ++i) r[i] = (short)f2bf(f[i]);
    return r;
}

// ---------------------------------------------------------------------------
// C[M x 128] = act(A[M x K] @ W[K x 128]) via v_mfma_f32_16x16x32_bf16.
// 256 thr = 4 waves; wave w: rows m0..m0+15, all 128 cols (8 n-tiles).
// A given as A1 (k<128) and optional A2 (k>=128). W pre-packed (see above).
// A-operand layout: A[m=lane&15][k=quad*8+j]; C/D: col=lane&15, row=quad*4+reg.
// ---------------------------------------------------------------------------
__global__ __launch_bounds__(256) void mfma_gemm_kernel(
    const void* A1, int mode1, const void* A2, int mode2,
    const unsigned short* __restrict__ wpk, int M, int ksteps,
    int relu, int outmode, void* out, int out_off)
{
    const int wave = threadIdx.x >> 6;
    const int lane = threadIdx.x & 63;
    const int q = lane >> 4;
    const int lm = lane & 15;
    const int m0 = blockIdx.x * 64 + wave * 16;
    const int mrow = m0 + lm;
    const bool valid = (mrow < M);
    const int bf = g_flag;

    v4f acc[8];
#pragma unroll
    for (int t = 0; t < 8; ++t) acc[t] = {0.f, 0.f, 0.f, 0.f};

    for (int ks = 0; ks < ksteps; ++ks) {
        const int kk = ks * 32 + q * 8;
        v8s a = {0, 0, 0, 0, 0, 0, 0, 0};
        if (valid) {
            if (kk < 128) a = loadA(A1, (size_t)mrow * 128 + kk, mode1, bf);
            else          a = loadA(A2, (size_t)mrow * 128 + (kk - 128), mode2, bf);
        }
        const unsigned short* wb = wpk + (size_t)(ks * 4 + q) * 128 * 8;
#pragma unroll
        for (int t = 0; t < 8; ++t) {
            const v8s b = *(const v8s*)(wb + (t * 16 + lm) * 8);
            acc[t] = __builtin_amdgcn_mfma_f32_16x16x32_bf16(a, b, acc[t], 0, 0, 0);
        }
    }

#pragma unroll
    for (int t = 0; t < 8; ++t) {
#pragma unroll
        for (int r = 0; r < 4; ++r) {
            const int row = m0 + q * 4 + r;
            if (row < M) {
                float v = acc[t][r];
                if (relu && v < 0.f) v = 0.f;
                const int col = t * 16 + lm;
                if (outmode == 0)
                    ((unsigned short*)out)[(size_t)row * 128 + col] = f2bf(v);
                else
                    stOut(out, out_off + row * 128 + col, v, bf);
            }
        }
    }
}

// xs_agg[idx[g,k]] += w[g,k] * hg[g]   (f32 atomics, coalesced per wave)
__global__ __launch_bounds__(128) void scatter_kernel(
    const unsigned short* __restrict__ hgb, const int* __restrict__ idx,
    const float* __restrict__ w, float* __restrict__ xs_agg) {
    const int g = blockIdx.x;
    const int j = threadIdx.x;
    const float m = bf2f(hgb[g * DD + j]);
#pragma unroll
    for (int k = 0; k < KK; ++k) {
        const int s = idx[g * KK + k];
        const float wt = w[g * KK + k];
        atomicAdd(&xs_agg[s * DD + j], m * wt);
    }
}

// agg_g[g] = sum_k w[g,k] * hs[idx[g,k]]  (bf16 out)
__global__ __launch_bounds__(128) void gather_kernel(
    const unsigned short* __restrict__ hsb, const int* __restrict__ idx,
    const float* __restrict__ w, unsigned short* __restrict__ agg) {
    const int g = blockIdx.x;
    const int j = threadIdx.x;
    float acc = 0.f;
#pragma unroll
    for (int k = 0; k < KK; ++k)
        acc += w[g * KK + k] * bf2f(hsb[idx[g * KK + k] * DD + j]);
    agg[g * DD + j] = f2bf(acc);
}

extern "C" void kernel_launch(void* const* d_in, const int* in_sizes, int n_in,
                              void* d_out, int out_size, void* d_ws, size_t ws_size,
                              hipStream_t stream)
{
    const void* xs       = d_in[0];
    const void* xg       = d_in[1];
    const void* pos_s    = d_in[2];
    const void* pos_g    = d_in[3];
    const void* W_s_pre  = d_in[4];
    const void* W_g_pre  = d_in[5];
    const void* W_gs     = d_in[6];
    const void* W_sg     = d_in[7];
    const void* W_s_post = d_in[8];
    const void* W_g_post = d_in[9];
    (void)in_sizes; (void)n_in; (void)out_size; (void)ws_size;

    // scratch carve-out from d_ws (~26 MB; round-5 proved >= 31.8 MB usable)
    char* ws = (char*)d_ws;
    size_t off_b = 0;
    auto alloc = [&](size_t bytes) -> void* {
        void* p = ws + off_b;
        off_b = (off_b + bytes + 255) & ~((size_t)255);
        return p;
    };
    unsigned short* hsb    = (unsigned short*)alloc((size_t)N_S * DD * 2);
    unsigned short* hgb    = (unsigned short*)alloc((size_t)N_G * DD * 2);
    unsigned short* aggg   = (unsigned short*)alloc((size_t)N_G * DD * 2);
    float*          xs_agg = (float*) alloc((size_t)N_S * DD * 4);
    float*          wf_s   = (float*) alloc((size_t)DD * DD * 4);
    float*          wf_g   = (float*) alloc((size_t)DD * DD * 4);
    unsigned short* wpk_ps = (unsigned short*)alloc((size_t)DD * DD * 2);       // pre_s W
    unsigned short* wpk_pg = (unsigned short*)alloc((size_t)DD * DD * 2);       // pre_g W
    unsigned short* wpk_cs = (unsigned short*)alloc((size_t)2 * DD * DD * 2);   // concat W (s)
    unsigned short* wpk_cg = (unsigned short*)alloc((size_t)2 * DD * DD * 2);   // concat W (g)
    int*            idx    = (int*)   alloc((size_t)NE * 4);
    float*          w      = (float*) alloc((size_t)NE * 4);
    int*            ccnt   = (int*)   alloc((size_t)CELLS * 4);
    int*            coff   = (int*)   alloc((size_t)CELLS * 4);
    int*            ccur   = (int*)   alloc((size_t)CELLS * 4);
    float4*         scell  = (float4*)alloc((size_t)N_S * 16);

    hipMemsetAsync(xs_agg, 0, (size_t)N_S * DD * 4, stream);

    detect_kernel<<<1, 256, 0, stream>>>(pos_g, ccnt);

    // surface-point grid CSR + exact kNN
    cell_count_kernel<<<(N_S + 255) / 256, 256, 0, stream>>>(pos_s, ccnt);
    cell_scan_kernel<<<1, 1024, 0, stream>>>(ccnt, coff, ccur);
    cell_fill_kernel<<<(N_S + 255) / 256, 256, 0, stream>>>(pos_s, ccur, scell);
    knn_grid_kernel<<<N_G, 64, 0, stream>>>(pos_g, coff, ccnt, scell, idx, w);

    // weight prep
    pack_w_kernel<<<(DD * DD + 255) / 256, 256, 0, stream>>>(W_s_pre, wpk_ps, DD);
    pack_w_kernel<<<(DD * DD + 255) / 256, 256, 0, stream>>>(W_g_pre, wpk_pg, DD);
    wfuse_kernel<<<DD, DD, 0, stream>>>(W_gs, W_s_post, wf_s);
    wfuse_kernel<<<DD, DD, 0, stream>>>(W_sg, W_g_post, wf_g);
    pack_wc_kernel<<<(2 * DD * DD + 255) / 256, 256, 0, stream>>>(W_s_post, wf_s, wpk_cs);
    pack_wc_kernel<<<(2 * DD * DD + 255) / 256, 256, 0, stream>>>(W_g_post, wf_g, wpk_cg);

    // pre blocks: hs = xs @ W_s_pre, hg = xg @ W_g_pre  (bf16 out)
    mfma_gemm_kernel<<<(N_S + 63) / 64, 256, 0, stream>>>(
        xs, 2, nullptr, 0, wpk_ps, N_S, 4, 0, 0, hsb, 0);
    mfma_gemm_kernel<<<(N_G + 63) / 64, 256, 0, stream>>>(
        xg, 2, nullptr, 0, wpk_pg, N_G, 4, 0, 0, hgb, 0);

    // message aggregation
    scatter_kernel<<<N_G, 128, 0, stream>>>(hgb, idx, w, xs_agg);
    gather_kernel<<<N_G, 128, 0, stream>>>(hsb, idx, w, aggg);

    // post blocks: relu(concat(h, agg) @ Wc)
    mfma_gemm_kernel<<<(N_S + 63) / 64, 256, 0, stream>>>(
        hsb, 0, xs_agg, 1, wpk_cs, N_S, 8, 1, 1, d_out, 0);
    mfma_gemm_kernel<<<(N_G + 63) / 64, 256, 0, stream>>>(
        hgb, 0, aggg, 0, wpk_cg, N_G, 8, 1, 1, d_out, N_S * DD);
}

// Round 7
// 194.919 us; speedup vs baseline: 8.3382x; 1.3185x over previous
//
#include <hip/hip_runtime.h>
#include <stdint.h>

#define N_S 30000
#define N_G 3000
#define DD  128
#define KK  16
#define NE  (N_G * KK)
#define NC  16            // cells per axis
#define CELLS (NC * NC * NC)
#define CH  3.75f         // cell size (60/16), exactly representable
#define CAP 32            // fixed slots per cell; overflow list keeps exactness

using v8s = __attribute__((ext_vector_type(8))) short;   // 8 bf16 (4 VGPRs)
using v4f = __attribute__((ext_vector_type(4))) float;   // MFMA accumulator

// Only device-side-accessed global state (never passed as a kernel arg from host).
__device__ int g_flag;   // 1 = tensors are bf16, 0 = f32

__device__ __forceinline__ float bf2f(unsigned short u) {
    union { unsigned int i; float f; } v; v.i = ((unsigned int)u) << 16; return v.f;
}
__device__ __forceinline__ unsigned short f2bf(float f) {
    union { float f; unsigned int i; } v; v.f = f;
    unsigned int x = v.i;
    return (unsigned short)((x + 0x7fffu + ((x >> 16) & 1u)) >> 16);
}
__device__ __forceinline__ float ldIn(const void* p, int i, int bf) {
    return bf ? bf2f(((const unsigned short*)p)[i]) : ((const float*)p)[i];
}
__device__ __forceinline__ void stOut(void* p, int i, float v, int bf) {
    if (bf) ((unsigned short*)p)[i] = f2bf(v);
    else    ((float*)p)[i] = v;
}
__device__ __forceinline__ int cellOf(float x) {
    int c = (int)(x * (1.0f / CH));
    if (c < 0) c = 0; if (c > NC - 1) c = NC - 1;
    return c;
}

// dtype detect + zero ccnt/novf.
__global__ void detect_kernel(const void* pos_g, int* __restrict__ ccnt,
                              int* __restrict__ novf) {
    const unsigned int* w = (const unsigned int*)pos_g;
    __shared__ int sv[256];
    const int t = threadIdx.x;
    for (int i = t; i < CELLS; i += 256) ccnt[i] = 0;
    if (t == 0) *novf = 0;
    int votes = 0;
    for (int i = t; i < 4500; i += 256) {
        unsigned int b = (w[i] >> 8) & 0xFFu;
        if (b >= 0x3Eu && b <= 0x42u) votes++;
    }
    sv[t] = votes; __syncthreads();
    for (int o = 128; o > 0; o >>= 1) {
        if (t < o) sv[t] += sv[t + o];
        __syncthreads();
    }
    if (t == 0) g_flag = (sv[0] > 2250) ? 1 : 0;
}

// direct binning: scell[cid*CAP+slot]; overflow (rare/never) to exact side list
__global__ void grid_fill_kernel(const void* pos_s, int* __restrict__ ccnt,
                                 float4* __restrict__ scell,
                                 float4* __restrict__ ovf, int* __restrict__ novf) {
    const int p = blockIdx.x * 256 + threadIdx.x;
    if (p < N_S) {
        const int bf = g_flag;
        const float x = ldIn(pos_s, 3 * p + 0, bf);
        const float y = ldIn(pos_s, 3 * p + 1, bf);
        const float z = ldIn(pos_s, 3 * p + 2, bf);
        const int cid = (cellOf(x) * NC + cellOf(y)) * NC + cellOf(z);
        const int slot = atomicAdd(&ccnt[cid], 1);
        const float4 pt = make_float4(x, y, z, __int_as_float(p));
        if (slot < CAP) scell[cid * CAP + slot] = pt;
        else            ovf[atomicAdd(novf, 1)] = pt;
    }
}

// ---------------------------------------------------------------------------
// Grid-accelerated exact kNN. One wave per graph node. f64 distances (exact
// for bf16/f32-origin coords), lower-index tie-break. Shell expansion with
// conservative stop rule; fixed-capacity cells + overflow list keep exactness.
// ---------------------------------------------------------------------------
__global__ __launch_bounds__(64) void knn_grid_kernel(
    const void* pos_g, const int* __restrict__ ccnt,
    const float4* __restrict__ scell,
    const float4* __restrict__ ovf, const int* __restrict__ novf_p,
    int* __restrict__ idx_out, float* __restrict__ w_out)
{
    __shared__ unsigned short map16[64 * CAP];   // pos -> owning slot (4 KB)
    __shared__ int s_pref[64];
    __shared__ int s_base[64];

    const int g = blockIdx.x;
    const int t = threadIdx.x;
    const int bf = g_flag;

    const float gxf = ldIn(pos_g, 3 * g + 0, bf);
    const float gyf = ldIn(pos_g, 3 * g + 1, bf);
    const float gzf = ldIn(pos_g, 3 * g + 2, bf);
    const double gx = (double)gxf, gy = (double)gyf, gz = (double)gzf;
    const int cx = cellOf(gxf), cy = cellOf(gyf), cz = cellOf(gzf);

    double bk[KK]; int bi[KK];
#pragma unroll
    for (int j = 0; j < KK; ++j) { bk[j] = 1e300; bi[j] = 0x7fffffff; }

    // overflow candidates first (almost always zero)
    const int novf = *novf_p;
    for (int i = t; i < novf; i += 64) {
        const float4 cd = ovf[i];
        const double ddx = gx - (double)cd.x, ddy = gy - (double)cd.y, ddz = gz - (double)cd.z;
        const double d2 = ddx * ddx + ddy * ddy + ddz * ddz;
        const int sidx = __float_as_int(cd.w);
        if (d2 > bk[KK - 1] || (d2 == bk[KK - 1] && sidx > bi[KK - 1])) continue;
        double ck = d2; int ci2 = sidx;
#pragma unroll
        for (int j = 0; j < KK; ++j) {
            const bool less = (ck < bk[j]) || (ck == bk[j] && ci2 < bi[j]);
            const double nk = less ? ck : bk[j]; const int ni = less ? ci2 : bi[j];
            const double ok = less ? bk[j] : ck; const int oi = less ? bi[j] : ci2;
            bk[j] = nk; bi[j] = ni; ck = ok; ci2 = oi;
        }
    }

    bool done = false;
    for (int R = 1; R <= NC && !done; ++R) {
        const int S = 2 * R + 1;
        const int Scells = S * S * S;
        for (int cb = 0; cb < Scells; cb += 64) {
            const int ci = cb + t;
            int cnt = 0, base = 0;
            if (ci < Scells) {
                const int dz = ci % S - R;
                const int dy = (ci / S) % S - R;
                const int dx = ci / (S * S) - R;
                int ax = dx < 0 ? -dx : dx, ay = dy < 0 ? -dy : dy, az = dz < 0 ? -dz : dz;
                int cheb = ax > ay ? ax : ay; if (az > cheb) cheb = az;
                const bool want = (R == 1) ? true : (cheb == R);
                const int X = cx + dx, Y = cy + dy, Z = cz + dz;
                if (want && X >= 0 && X < NC && Y >= 0 && Y < NC && Z >= 0 && Z < NC) {
                    const int cid = (X * NC + Y) * NC + Z;
                    int c = ccnt[cid]; if (c > CAP) c = CAP;
                    cnt = c; base = cid * CAP;
                }
            }
            int incl = cnt;
            for (int d = 1; d < 64; d <<= 1) {
                int v = __shfl_up(incl, d);
                if (t >= d) incl += v;
            }
            const int total = __shfl(incl, 63);
            const int pref = incl - cnt;
            s_pref[t] = pref; s_base[t] = base;
            __syncthreads();
            for (int i = 0; i < cnt; ++i) map16[pref + i] = (unsigned short)t;
            __syncthreads();
            for (int pos = t; pos < total; pos += 64) {
                const int slot = map16[pos];
                const float4 cd = scell[s_base[slot] + (pos - s_pref[slot])];
                const double ddx = gx - (double)cd.x;
                const double ddy = gy - (double)cd.y;
                const double ddz = gz - (double)cd.z;
                const double d2 = ddx * ddx + ddy * ddy + ddz * ddz;
                const int sidx = __float_as_int(cd.w);
                if (d2 > bk[KK - 1]) continue;
                if (d2 == bk[KK - 1] && sidx > bi[KK - 1]) continue;
                double ck = d2; int ci2 = sidx;
#pragma unroll
                for (int j = 0; j < KK; ++j) {
                    const bool less = (ck < bk[j]) || (ck == bk[j] && ci2 < bi[j]);
                    const double nk = less ? ck : bk[j]; const int ni = less ? ci2 : bi[j];
                    const double ok = less ? bk[j] : ck; const int oi = less ? bi[j] : ci2;
                    bk[j] = nk; bi[j] = ni; ck = ok; ci2 = oi;
                }
            }
            __syncthreads();
        }
        // stop test: m = min distance from query to unexamined region
        double m = 1e300;
        if (cx - R > 0)      { double d = gx - (double)(cx - R) * 3.75; if (d < m) m = d; }
        if (cx + R < NC - 1) { double d = (double)(cx + R + 1) * 3.75 - gx; if (d < m) m = d; }
        if (cy - R > 0)      { double d = gy - (double)(cy - R) * 3.75; if (d < m) m = d; }
        if (cy + R < NC - 1) { double d = (double)(cy + R + 1) * 3.75 - gy; if (d < m) m = d; }
        if (cz - R > 0)      { double d = gz - (double)(cz - R) * 3.75; if (d < m) m = d; }
        if (cz + R < NC - 1) { double d = (double)(cz + R + 1) * 3.75 - gz; if (d < m) m = d; }
        if (m < 0.0) m = 0.0;
        const double m2 = m * m * (1.0 - 1e-12);
        int cntlt = 0;
#pragma unroll
        for (int j = 0; j < KK; ++j) cntlt += (bk[j] < m2) ? 1 : 0;
        for (int d = 1; d < 64; d <<= 1) cntlt += __shfl_xor(cntlt, d);
        if (cntlt >= KK) done = true;
    }

    // merge: 16 rounds of wave-argmin over sorted per-lane lists, register shift
    for (int p = 0; p < KK; ++p) {
        double key = bk[0]; int sid = bi[0];
        for (int d = 1; d < 64; d <<= 1) {
            const double ok = __shfl_xor(key, d);
            const int    os = __shfl_xor(sid, d);
            if (ok < key || (ok == key && os < sid)) { key = ok; sid = os; }
        }
        if (t == 0) {
            idx_out[g * KK + p] = sid;
            w_out[g * KK + p] = expf((float)(-key) * (1.0f / 12.5f));
        }
        const bool win = (bk[0] == key) && (bi[0] == sid);
        if (win) {
#pragma unroll
            for (int j = 0; j < KK - 1; ++j) { bk[j] = bk[j + 1]; bi[j] = bi[j + 1]; }
            bk[KK - 1] = 1e300; bi[KK - 1] = 0x7fffffff;
        }
    }
}

// ---------------------------------------------------------------------------
// All weight prep in one kernel. Packed layout: (k,n) -> [((ks*4+q)*128+n)*8+i],
// k = ks*32+q*8+i. Blocks: 0-127 W_s_pre row; 128-255 W_g_pre row; 256-511
// combined_s row (k<128: W_s_post top; else Wf_s = W_gs @ W_s_post[128:]);
// 512-767 combined_g likewise.
// ---------------------------------------------------------------------------
__global__ __launch_bounds__(128) void pack_kernel(
    const void* Wsp, const void* Wgp, const void* Wgs, const void* Wsg,
    const void* Wspost, const void* Wgpost,
    unsigned short* __restrict__ wpk_ps, unsigned short* __restrict__ wpk_pg,
    unsigned short* __restrict__ wpk_cs, unsigned short* __restrict__ wpk_cg)
{
    __shared__ float row[DD];
    const int b = blockIdx.x, j = threadIdx.x, bf = g_flag;
    float v; unsigned short* dst; int k;
    if (b < 128) {
        k = b; v = ldIn(Wsp, k * DD + j, bf); dst = wpk_ps;
    } else if (b < 256) {
        k = b - 128; v = ldIn(Wgp, k * DD + j, bf); dst = wpk_pg;
    } else {
        const int which_g = (b >= 512);
        const int r = which_g ? (b - 512) : (b - 256);
        const void* W1 = which_g ? Wsg : Wgs;
        const void* Wp = which_g ? Wgpost : Wspost;
        dst = which_g ? wpk_cg : wpk_cs;
        k = r;
        if (r < 128) {
            v = ldIn(Wp, r * DD + j, bf);
        } else {
            row[j] = ldIn(W1, (r - 128) * DD + j, bf);
            __syncthreads();
            float acc = 0.f;
            for (int m = 0; m < DD; ++m) acc += row[m] * ldIn(Wp, (DD + m) * DD + j, bf);
            v = acc;
        }
    }
    const int ks = k >> 5, q = (k >> 3) & 3, i = k & 7;
    dst[((ks * 4 + q) * 128 + j) * 8 + i] = f2bf(v);
}

// A-fragment load: mode 0 = bf16 ptr, 1 = f32 ptr, 2 = raw input (dtype per bf).
__device__ __forceinline__ v8s loadA(const void* A, size_t off, int mode, int bf) {
    if (mode == 0 || (mode == 2 && bf)) {
        return *(const v8s*)((const unsigned short*)A + off);
    }
    const float* f = (const float*)A + off;
    v8s r;
#pragma unroll
    for (int i = 0; i < 8; ++i) r[i] = (short)f2bf(f[i]);
    return r;
}

// pre blocks: hs = xs@W_s_pre, hg = xg@W_g_pre (bf16 out); s-blocks also zero xs_agg.
__global__ __launch_bounds__(256) void mfma_pre_kernel(
    const void* xs, const void* xg,
    const unsigned short* __restrict__ wpk_ps, const unsigned short* __restrict__ wpk_pg,
    unsigned short* __restrict__ hsb, unsigned short* __restrict__ hgb,
    float* __restrict__ xs_agg, int nbs)
{
    const int b = blockIdx.x;
    const void* A; const unsigned short* wpk; unsigned short* out; int M, m0;
    const bool is_s = (b < nbs);
    if (is_s) { A = xs; wpk = wpk_ps; out = hsb; M = N_S; m0 = b * 64; }
    else      { A = xg; wpk = wpk_pg; out = hgb; M = N_G; m0 = (b - nbs) * 64; }

    const int wave = threadIdx.x >> 6, lane = threadIdx.x & 63;
    const int q = lane >> 4, lm = lane & 15;
    const int mb = m0 + wave * 16;
    const int mrow = mb + lm;
    const bool valid = (mrow < M);
    const int bf = g_flag;

    v4f acc[8];
#pragma unroll
    for (int t = 0; t < 8; ++t) acc[t] = {0.f, 0.f, 0.f, 0.f};
    for (int ks = 0; ks < 4; ++ks) {
        v8s a = {0,0,0,0,0,0,0,0};
        if (valid) a = loadA(A, (size_t)mrow * 128 + ks * 32 + q * 8, 2, bf);
        const unsigned short* wb = wpk + (size_t)(ks * 4 + q) * 128 * 8;
#pragma unroll
        for (int t = 0; t < 8; ++t) {
            const v8s bfr = *(const v8s*)(wb + (t * 16 + lm) * 8);
            acc[t] = __builtin_amdgcn_mfma_f32_16x16x32_bf16(a, bfr, acc[t], 0, 0, 0);
        }
    }
#pragma unroll
    for (int t = 0; t < 8; ++t)
#pragma unroll
        for (int r = 0; r < 4; ++r) {
            const int row = mb + q * 4 + r;
            if (row < M) out[(size_t)row * 128 + t * 16 + lm] = f2bf(acc[t][r]);
        }
    if (is_s) {   // zero this block's slice of xs_agg (replaces memset dispatch)
        for (int i = threadIdx.x; i < 64 * 128; i += 256) {
            const int r = m0 + (i >> 7);
            if (r < N_S) xs_agg[(size_t)r * 128 + (i & 127)] = 0.f;
        }
    }
}

// scatter (blocks 0..N_G-1) + gather (blocks N_G..2N_G-1)
__global__ __launch_bounds__(128) void scatgath_kernel(
    const unsigned short* __restrict__ hsb, const unsigned short* __restrict__ hgb,
    const int* __restrict__ idx, const float* __restrict__ w,
    float* __restrict__ xs_agg, unsigned short* __restrict__ aggg)
{
    const int b = blockIdx.x, j = threadIdx.x;
    if (b < N_G) {
        const float m = bf2f(hgb[b * DD + j]);
#pragma unroll
        for (int k = 0; k < KK; ++k)
            atomicAdd(&xs_agg[(size_t)idx[b * KK + k] * DD + j], m * w[b * KK + k]);
    } else {
        const int g = b - N_G;
        float acc = 0.f;
#pragma unroll
        for (int k = 0; k < KK; ++k)
            acc += w[g * KK + k] * bf2f(hsb[(size_t)idx[g * KK + k] * DD + j]);
        aggg[g * DD + j] = f2bf(acc);
    }
}

// post blocks: out = relu(concat(h, agg) @ Wc); s-part then g-part (row ranges).
__global__ __launch_bounds__(256) void mfma_post_kernel(
    const unsigned short* __restrict__ hsb, const float* __restrict__ xs_agg,
    const unsigned short* __restrict__ hgb, const unsigned short* __restrict__ aggg,
    const unsigned short* __restrict__ wpk_cs, const unsigned short* __restrict__ wpk_cg,
    void* out, int nbs)
{
    const int b = blockIdx.x;
    const void* A1; const void* A2; int mode2; const unsigned short* wpk;
    int M, m0, ooff;
    if (b < nbs) { A1 = hsb; A2 = xs_agg; mode2 = 1; wpk = wpk_cs; M = N_S; m0 = b * 64; ooff = 0; }
    else { A1 = hgb; A2 = aggg; mode2 = 0; wpk = wpk_cg; M = N_G; m0 = (b - nbs) * 64; ooff = N_S * DD; }

    const int wave = threadIdx.x >> 6, lane = threadIdx.x & 63;
    const int q = lane >> 4, lm = lane & 15;
    const int mb = m0 + wave * 16;
    const int mrow = mb + lm;
    const bool valid = (mrow < M);
    const int bf = g_flag;

    v4f acc[8];
#pragma unroll
    for (int t = 0; t < 8; ++t) acc[t] = {0.f, 0.f, 0.f, 0.f};
    for (int ks = 0; ks < 8; ++ks) {
        const int kk = ks * 32 + q * 8;
        v8s a = {0,0,0,0,0,0,0,0};
        if (valid) {
            if (kk < 128) a = loadA(A1, (size_t)mrow * 128 + kk, 0, bf);
            else          a = loadA(A2, (size_t)mrow * 128 + (kk - 128), mode2, bf);
        }
        const unsigned short* wb = wpk + (size_t)(ks * 4 + q) * 128 * 8;
#pragma unroll
        for (int t = 0; t < 8; ++t) {
            const v8s bfr = *(const v8s*)(wb + (t * 16 + lm) * 8);
            acc[t] = __builtin_amdgcn_mfma_f32_16x16x32_bf16(a, bfr, acc[t], 0, 0, 0);
        }
    }
#pragma unroll
    for (int t = 0; t < 8; ++t)
#pragma unroll
        for (int r = 0; r < 4; ++r) {
            const int row = mb + q * 4 + r;
            if (row < M) {
                float v = acc[t][r];
                if (v < 0.f) v = 0.f;
                stOut(out, ooff + row * DD + t * 16 + lm, v, bf);
            }
        }
}

extern "C" void kernel_launch(void* const* d_in, const int* in_sizes, int n_in,
                              void* d_out, int out_size, void* d_ws, size_t ws_size,
                              hipStream_t stream)
{
    const void* xs       = d_in[0];
    const void* xg       = d_in[1];
    const void* pos_s    = d_in[2];
    const void* pos_g    = d_in[3];
    const void* W_s_pre  = d_in[4];
    const void* W_g_pre  = d_in[5];
    const void* W_gs     = d_in[6];
    const void* W_sg     = d_in[7];
    const void* W_s_post = d_in[8];
    const void* W_g_post = d_in[9];
    (void)in_sizes; (void)n_in; (void)out_size; (void)ws_size;

    char* ws = (char*)d_ws;
    size_t off_b = 0;
    auto alloc = [&](size_t bytes) -> void* {
        void* p = ws + off_b;
        off_b = (off_b + bytes + 255) & ~((size_t)255);
        return p;
    };
    unsigned short* hsb    = (unsigned short*)alloc((size_t)N_S * DD * 2);
    unsigned short* hgb    = (unsigned short*)alloc((size_t)N_G * DD * 2);
    unsigned short* aggg   = (unsigned short*)alloc((size_t)N_G * DD * 2);
    float*          xs_agg = (float*) alloc((size_t)N_S * DD * 4);
    unsigned short* wpk_ps = (unsigned short*)alloc((size_t)DD * DD * 2);
    unsigned short* wpk_pg = (unsigned short*)alloc((size_t)DD * DD * 2);
    unsigned short* wpk_cs = (unsigned short*)alloc((size_t)2 * DD * DD * 2);
    unsigned short* wpk_cg = (unsigned short*)alloc((size_t)2 * DD * DD * 2);
    int*            idx    = (int*)   alloc((size_t)NE * 4);
    float*          w      = (float*) alloc((size_t)NE * 4);
    int*            ccnt   = (int*)   alloc((size_t)CELLS * 4);
    int*            novf   = (int*)   alloc(256);
    float4*         scell  = (float4*)alloc((size_t)CELLS * CAP * 16);
    float4*         ovf    = (float4*)alloc((size_t)N_S * 16);

    const int nbs = (N_S + 63) / 64;
    const int nbg = (N_G + 63) / 64;

    detect_kernel<<<1, 256, 0, stream>>>(pos_g, ccnt, novf);
    grid_fill_kernel<<<(N_S + 255) / 256, 256, 0, stream>>>(pos_s, ccnt, scell, ovf, novf);
    knn_grid_kernel<<<N_G, 64, 0, stream>>>(pos_g, ccnt, scell, ovf, novf, idx, w);
    pack_kernel<<<768, 128, 0, stream>>>(W_s_pre, W_g_pre, W_gs, W_sg,
                                         W_s_post, W_g_post,
                                         wpk_ps, wpk_pg, wpk_cs, wpk_cg);
    mfma_pre_kernel<<<nbs + nbg, 256, 0, stream>>>(xs, xg, wpk_ps, wpk_pg,
                                                   hsb, hgb, xs_agg, nbs);
    scatgath_kernel<<<2 * N_G, 128, 0, stream>>>(hsb, hgb, idx, w, xs_agg, aggg);
    mfma_post_kernel<<<nbs + nbg, 256, 0, stream>>>(hsb, xs_agg, hgb, aggg,
                                                    wpk_cs, wpk_cg, d_out, nbs);
}